// Round 5
// baseline (398.568 us; speedup 1.0000x reference)
//
#include <hip/hip_runtime.h>
#include <hip/hip_fp16.h>

#define E_DIM 2048
#define S_LEN 2048
#define NH 32
#define HD 64
#define KV_DIM 512
#define QKV_N 3072      // E + 2*KV
#define M_ROWS 4096     // B*S
#define QK_SCALE 0.18033688011112042f  // (1/sqrt(64)) * log2(e)

typedef __bf16 bf16x8 __attribute__((ext_vector_type(8)));
typedef float f32x4 __attribute__((ext_vector_type(4)));

__device__ __forceinline__ void async_lds16(const __bf16* g, __bf16* l) {
    __builtin_amdgcn_global_load_lds(
        (const __attribute__((address_space(1))) void*)g,
        (__attribute__((address_space(3))) void*)l, 16, 0, 0);
}

#define BAR() asm volatile("s_barrier" ::: "memory")

// ---------------- fp32 -> bf16 elementwise convert ----------------
__global__ void k_convert(const float* __restrict__ x, __bf16* __restrict__ xb, int n) {
    int i = (blockIdx.x * blockDim.x + threadIdx.x) * 4;
    if (i < n) {
        float4 v = *(const float4*)(x + i);
        xb[i + 0] = (__bf16)v.x;
        xb[i + 1] = (__bf16)v.y;
        xb[i + 2] = (__bf16)v.z;
        xb[i + 3] = (__bf16)v.w;
    }
}

// ---------------- all four weight transposes in one launch ----------------
__global__ void k_transpose_all(const float* __restrict__ Wq, const float* __restrict__ Wk,
                                const float* __restrict__ Wv, const float* __restrict__ Wo,
                                __bf16* __restrict__ WtAll, __bf16* __restrict__ WoT) {
    const int which = blockIdx.z;
    const float* W;
    __bf16* dst;
    int N;
    float scale = 1.f;
    if (which == 0)      { W = Wq; dst = WtAll;                                    N = E_DIM;  scale = QK_SCALE; }
    else if (which == 1) { W = Wk; dst = WtAll + (size_t)E_DIM * E_DIM;            N = KV_DIM; }
    else if (which == 2) { W = Wv; dst = WtAll + (size_t)(E_DIM + KV_DIM) * E_DIM; N = KV_DIM; }
    else                 { W = Wo; dst = WoT;                                      N = E_DIM;  }
    const int n0 = blockIdx.x * 32;
    if (n0 >= N) return;
    const int k0 = blockIdx.y * 32;
    __shared__ float tile[32][33];
    int tx = threadIdx.x, ty = threadIdx.y;
#pragma unroll
    for (int j = 0; j < 4; ++j)
        tile[ty + j * 8][tx] = W[(size_t)(k0 + ty + j * 8) * N + n0 + tx];
    __syncthreads();
#pragma unroll
    for (int j = 0; j < 4; ++j)
        dst[(size_t)(n0 + ty + j * 8) * E_DIM + k0 + tx] = (__bf16)(tile[tx][ty + j * 8] * scale);
}

// ---------------- 256x256 8-phase bf16 GEMM (QKV projection) ----------------
#define STG(g, l, bb, hh, kt) do {                                                              \
    async_lds16((g) + (size_t)((hh) * 128) * K + (size_t)(kt) * 64,                             \
                (l) + (bb) * 16384 + (hh) * 8192);                                              \
    async_lds16((g) + (size_t)((hh) * 128 + 64) * K + (size_t)(kt) * 64,                        \
                (l) + (bb) * 16384 + (hh) * 8192 + 4096);                                       \
} while (0)

#define LDA_(p, mq) do {                                                                        \
    _Pragma("unroll") for (int i_ = 0; i_ < 4; ++i_) {                                          \
        const char* rp_ = pAs + (p) * 32768 + ((mq) * 128 + rA + i_ * 16) * 128;                \
        a[i_][0] = *(const bf16x8*)(rp_ + swzk0);                                               \
        a[i_][1] = *(const bf16x8*)(rp_ + swzk1);                                               \
    }                                                                                           \
} while (0)

#define LDB_(p, nq, b) do {                                                                     \
    _Pragma("unroll") for (int j_ = 0; j_ < 2; ++j_) {                                          \
        const char* rp_ = pBs + (p) * 32768 + ((nq) * 128 + rB + j_ * 16) * 128;                \
        b[j_][0] = *(const bf16x8*)(rp_ + swzk0);                                               \
        b[j_][1] = *(const bf16x8*)(rp_ + swzk1);                                               \
    }                                                                                           \
} while (0)

#define MM(mq, nq, b) do {                                                                      \
    __builtin_amdgcn_s_setprio(1);                                                              \
    _Pragma("unroll") for (int i_ = 0; i_ < 4; ++i_)                                            \
    _Pragma("unroll") for (int j_ = 0; j_ < 2; ++j_) {                                          \
        acc[mq][nq][i_][j_] = __builtin_amdgcn_mfma_f32_16x16x32_bf16(                          \
            a[i_][0], b[j_][0], acc[mq][nq][i_][j_], 0, 0, 0);                                  \
        acc[mq][nq][i_][j_] = __builtin_amdgcn_mfma_f32_16x16x32_bf16(                          \
            a[i_][1], b[j_][1], acc[mq][nq][i_][j_], 0, 0, 0);                                  \
    }                                                                                           \
    __builtin_amdgcn_s_setprio(0);                                                              \
} while (0)

#define GROUP(p, kt, S1, S2, WAITSTMT) do {                                                     \
    LDA_(p, 0);                                                                                 \
    LDB_(p, 0, b0);                                                                             \
    if (S1) STG(gA, lA, (p) ^ 1, 1, (kt) + 1);                                                  \
    BAR(); MM(0, 0, b0); BAR();                                                                 \
    LDB_(p, 1, b1);                                                                             \
    if (S2) STG(gA, lA, (p), 0, (kt) + 2);                                                      \
    BAR(); MM(0, 1, b1); BAR();                                                                 \
    LDA_(p, 1);                                                                                 \
    if (S2) STG(gB, lB, (p), 0, (kt) + 2);                                                      \
    BAR(); MM(1, 1, b1); BAR();                                                                 \
    if (S2) STG(gB, lB, (p), 1, (kt) + 2);                                                      \
    WAITSTMT;                                                                                   \
    BAR(); MM(1, 0, b0); BAR();                                                                 \
} while (0)

__global__ __launch_bounds__(512, 2)
void k_gemm8(const __bf16* __restrict__ A, const __bf16* __restrict__ Bt,
             __bf16* __restrict__ C, int M, int N, int K) {
    __shared__ __attribute__((aligned(16))) __bf16 As[2][16384];
    __shared__ __attribute__((aligned(16))) __bf16 Bs[2][16384];
    const int T = K >> 6;              // K-tiles of 64; requires T >= 3
    const int nbx = N >> 8;
    const int bid = blockIdx.x;
    const int swz = (bid & 7) * ((int)gridDim.x >> 3) + (bid >> 3);
    const int m0 = (swz / nbx) << 8;
    const int n0 = (swz % nbx) << 8;

    const int t = threadIdx.x;
    const int lane = t & 63, w = t >> 6;
    const int quad = lane >> 4, l16 = lane & 15;
    const int wr = w >> 2, wc = w & 3;

    const int rbase = w * 8 + (lane >> 3);
    const int cswz = ((lane & 7) ^ (lane >> 3)) * 8;
    const __bf16* gA = A + (size_t)(m0 + rbase) * K + cswz;
    const __bf16* gB = Bt + (size_t)(n0 + rbase) * K + cswz;
    __bf16* lA = &As[0][0] + w * 512;
    __bf16* lB = &Bs[0][0] + w * 512;

    const int swzk0 = ((0 + quad) ^ (l16 & 7)) * 16;
    const int swzk1 = ((4 + quad) ^ (l16 & 7)) * 16;
    const int rA = wr * 64 + l16;
    const int rB = wc * 32 + l16;
    const char* pAs = (const char*)&As[0][0];
    const char* pBs = (const char*)&Bs[0][0];

    f32x4 acc[2][2][4][2] = {};
    bf16x8 a[4][2], b0[2][2], b1[2][2];

    STG(gA, lA, 0, 0, 0); STG(gA, lA, 0, 1, 0);
    STG(gB, lB, 0, 0, 0); STG(gB, lB, 0, 1, 0);
    STG(gA, lA, 1, 0, 1);
    STG(gB, lB, 1, 0, 1); STG(gB, lB, 1, 1, 1);
    asm volatile("s_waitcnt vmcnt(6)" ::: "memory");
    BAR();

    int p = 0;
    for (int kt = 0; kt < T - 2; ++kt) {
        GROUP(p, kt, 1, 1, asm volatile("s_waitcnt vmcnt(6)" ::: "memory"));
        p ^= 1;
    }
    GROUP(p, T - 2, 1, 0, asm volatile("s_waitcnt vmcnt(0)" ::: "memory"));
    p ^= 1;
    GROUP(p, T - 1, 0, 0, (void)0);

#pragma unroll
    for (int mq = 0; mq < 2; ++mq)
#pragma unroll
        for (int nq = 0; nq < 2; ++nq)
#pragma unroll
            for (int i = 0; i < 4; ++i)
#pragma unroll
                for (int j = 0; j < 2; ++j) {
                    const int row = m0 + mq * 128 + wr * 64 + i * 16 + quad * 4;
                    const int col = n0 + nq * 128 + wc * 32 + j * 16 + l16;
#pragma unroll
                    for (int r = 0; r < 4; ++r)
                        C[(size_t)(row + r) * N + col] = (__bf16)acc[mq][nq][i][j][r];
                }
    (void)M;
}

// ---------------- bf16 MFMA GEMM, BK=64 per barrier round (O-projection) ----------------
template <int OUT_F32>
__global__ __launch_bounds__(256, 2)
void k_gemm_bt(const __bf16* __restrict__ A, const __bf16* __restrict__ Bt,
               void* __restrict__ Cout, const float* __restrict__ bias,
               int M, int N, int K) {
    __shared__ __attribute__((aligned(16))) __bf16 As2[128 * 64];
    __shared__ __attribute__((aligned(16))) __bf16 Bs2[128 * 64];
    const int t = threadIdx.x;
    const int lane = t & 63, wave = t >> 6;
    const int quad = lane >> 4, l16 = lane & 15;
    const int wr = wave >> 1, wc = wave & 1;
    const int m0 = blockIdx.y * 128, n0 = blockIdx.x * 128;

    const int srow = t >> 2;
    const int sblk = (t & 3) ^ ((t >> 3) & 3);
    const __bf16* gA0 = A + (size_t)(m0 + srow) * K + sblk * 8;
    const __bf16* gA1 = gA0 + (size_t)64 * K;
    const __bf16* gB0 = Bt + (size_t)(n0 + srow) * K + sblk * 8;
    const __bf16* gB1 = gB0 + (size_t)64 * K;

    f32x4 acc[4][4] = {};

    for (int k0 = 0; k0 < K; k0 += 64) {
#pragma unroll
        for (int ks = 0; ks < 2; ++ks) {
            async_lds16(gA0 + k0 + ks * 32, As2 + ks * 4096 + wave * 512);
            async_lds16(gA1 + k0 + ks * 32, As2 + ks * 4096 + 2048 + wave * 512);
            async_lds16(gB0 + k0 + ks * 32, Bs2 + ks * 4096 + wave * 512);
            async_lds16(gB1 + k0 + ks * 32, Bs2 + ks * 4096 + 2048 + wave * 512);
        }
        __syncthreads();
#pragma unroll
        for (int ks = 0; ks < 2; ++ks) {
            bf16x8 af[4], bfr[4];
#pragma unroll
            for (int i = 0; i < 4; ++i) {
                const int row = wr * 64 + i * 16 + l16;
                af[i] = *(const bf16x8*)((const char*)As2 + ks * 8192 + row * 64 +
                                         ((quad ^ ((row >> 1) & 3)) * 16));
            }
#pragma unroll
            for (int j = 0; j < 4; ++j) {
                const int row = wc * 64 + j * 16 + l16;
                bfr[j] = *(const bf16x8*)((const char*)Bs2 + ks * 8192 + row * 64 +
                                          ((quad ^ ((row >> 1) & 3)) * 16));
            }
#pragma unroll
            for (int i = 0; i < 4; ++i)
#pragma unroll
                for (int j = 0; j < 4; ++j)
                    acc[i][j] = __builtin_amdgcn_mfma_f32_16x16x32_bf16(af[i], bfr[j], acc[i][j], 0, 0, 0);
        }
        __syncthreads();
    }

#pragma unroll
    for (int i = 0; i < 4; ++i)
#pragma unroll
        for (int j = 0; j < 4; ++j) {
            const int row = m0 + wr * 64 + i * 16 + quad * 4;
            const int col = n0 + wc * 64 + j * 16 + l16;
#pragma unroll
            for (int r = 0; r < 4; ++r) {
                float v = acc[i][j][r];
                if (OUT_F32) ((float*)Cout)[(size_t)(row + r) * N + col] = v + bias[col];
                else ((__bf16*)Cout)[(size_t)(row + r) * N + col] = (__bf16)v;
            }
        }
}

// ---------------- KV-split flash attention, 128-query blocks ----------------
// Each block: 128 queries (two 64-row sub-blocks) x 2 heads x one 512-key chunk.
// K/V staged ONCE per 128-key tile, shared by both sub-blocks -> per-tile fixed
// cost (V repack, DMA issue, 2 barrier drains) amortized over 2x queries.
// 16 q-blocks x {1,2,3,4} chunks = 40 x-units, grid (40,16,2) = 1280 blocks.
// pT head-double-buffered [4][2][512]; LDS total 41984 B -> 3 blocks/CU.
__global__ __launch_bounds__(256, 3)
void k_attn(const __bf16* __restrict__ qkv, __half* __restrict__ partO,
            float* __restrict__ partL) {
    const int xr = (int)(gridDim.x - 1 - blockIdx.x);   // reversed: biggest blocks first
    int qi, c;
    if (xr < 4)       { qi = xr;                   c = 0; }
    else if (xr < 12) { qi = 4 + ((xr - 4) >> 1);  c = (xr - 4) & 1; }
    else if (xr < 24) { qi = 8 + (xr - 12) / 3;    c = (xr - 12) % 3; }
    else              { qi = 12 + ((xr - 24) >> 2); c = (xr - 24) & 3; }
    const int q0 = qi * 128;
    const int k_lo = c * 512;
    const int k_hi = min(k_lo + 512, q0 + 128);

    const int gp = blockIdx.y;
    const int g = gp >> 1;
    const int h0 = g * 4 + (gp & 1) * 2;
    const int b = blockIdx.z;
    const int t = threadIdx.x;
    const int lane = t & 63, wave = t >> 6;
    const int quad = lane >> 4, l16 = lane & 15;

    __shared__ __attribute__((aligned(16))) __bf16 Kls[128 * 64];   // [key][d], swizzled
    __shared__ __attribute__((aligned(16))) __bf16 vT[64][136];     // [d][key 0..127], padded
    __shared__ __attribute__((aligned(16))) __bf16 pT[4][2][512];   // per-wave, per-head P^T

    const __bf16* base = qkv + (size_t)b * S_LEN * QKV_N;
    const int qr16 = wave * 16 + l16;   // per-sub query row offset within 64

    // Q fragments for both sub-blocks, both heads
    bf16x8 qf[2][2][2];
#pragma unroll
    for (int qs = 0; qs < 2; ++qs)
#pragma unroll
        for (int h = 0; h < 2; ++h)
#pragma unroll
            for (int s = 0; s < 2; ++s)
                qf[qs][h][s] = *(const bf16x8*)(base + (size_t)(q0 + qs * 64 + qr16) * QKV_N +
                                                (h0 + h) * HD + s * 32 + quad * 8);

    f32x4 o[2][2][4] = {};          // [qs][h][cc]
    float l_st[2][2] = {};

    const int vkey = lane * 2, vdg = wave * 16;
    const __bf16* vsrc = base + (E_DIM + KV_DIM) + g * HD + vdg;
    const __bf16* ksrc = base + E_DIM + g * HD;

    const int klocal = lane >> 3;
    const int kdblk = (lane & 7) ^ (klocal & 7);
    const __bf16* gk_base = ksrc + (size_t)(wave * 32 + klocal) * QKV_N + kdblk * 8;
    __bf16* lk_base = Kls + wave * 2048;

    const int pswz = (l16 >> 1) & 3;

    // one (sub-block, 64-key micro) pass: QK both heads, then per-half smx+pv
    auto micro_pass = [&](int kb, int m, int qs) {
        const int qsub0 = q0 + qs * 64;
        const int qrow = qsub0 + qr16;
        const bool diag = (kb == qsub0);
        f32x4 sA[4], sB[4];
        __builtin_amdgcn_s_setprio(1);
#pragma unroll
        for (int kt = 0; kt < 4; ++kt) {
            const int kr = m * 64 + kt * 16 + l16;
            const char* kb_ = (const char*)Kls + kr * 128;
            bf16x8 kf0 = *(const bf16x8*)(kb_ + ((quad ^ (kr & 7)) * 16));
            bf16x8 kf1 = *(const bf16x8*)(kb_ + (((4 + quad) ^ (kr & 7)) * 16));
            f32x4 z = {};
            z = __builtin_amdgcn_mfma_f32_16x16x32_bf16(kf0, qf[qs][0][0], z, 0, 0, 0);
            sA[kt] = __builtin_amdgcn_mfma_f32_16x16x32_bf16(kf1, qf[qs][0][1], z, 0, 0, 0);
            f32x4 ww = {};
            ww = __builtin_amdgcn_mfma_f32_16x16x32_bf16(kf0, qf[qs][1][0], ww, 0, 0, 0);
            sB[kt] = __builtin_amdgcn_mfma_f32_16x16x32_bf16(kf1, qf[qs][1][1], ww, 0, 0, 0);
        }
        __builtin_amdgcn_s_setprio(0);
#pragma unroll
        for (int half = 0; half < 2; ++half) {
            bf16x8 vf[4];
            const int koff = m * 64 + half * 32;
#pragma unroll
            for (int cc = 0; cc < 4; ++cc)
                vf[cc] = *(const bf16x8*)&vT[cc * 16 + l16][koff + quad * 8];
#pragma unroll
            for (int h = 0; h < 2; ++h) {
                f32x4* sc = h ? sB : sA;
                char* prow = (char*)&pT[wave][h][0] + l16 * 64;
                float lsum = 0.f;
#pragma unroll
                for (int u = 0; u < 2; ++u) {
                    const int kt = 2 * half + u;
                    f32x4 pv_;
#pragma unroll
                    for (int r = 0; r < 4; ++r) pv_[r] = exp2f(sc[kt][r]);
                    if (diag) {
                        const int kbase = kb + kt * 16 + quad * 4;
#pragma unroll
                        for (int r = 0; r < 4; ++r)
                            if (kbase + r > qrow) pv_[r] = 0.f;
                    }
#pragma unroll
                    for (int r = 0; r < 4; ++r) lsum += pv_[r];
                    __bf16 pb[4];
#pragma unroll
                    for (int r = 0; r < 4; ++r) pb[r] = (__bf16)pv_[r];
                    const int bi = (2 * u + (quad >> 1)) ^ pswz;
                    *(uint2*)(prow + bi * 16 + (quad & 1) * 8) = *(const uint2*)pb;
                }
                l_st[qs][h] += lsum;
                bf16x8 pf = *(const bf16x8*)(prow + ((quad ^ pswz) * 16));
                __builtin_amdgcn_s_setprio(1);
#pragma unroll
                for (int cc = 0; cc < 4; ++cc)
                    o[qs][h][cc] = __builtin_amdgcn_mfma_f32_16x16x32_bf16(vf[cc], pf, o[qs][h][cc], 0, 0, 0);
                __builtin_amdgcn_s_setprio(0);
            }
        }
    };

    for (int kv0 = k_lo; kv0 < k_hi; kv0 += 128) {
        // ---- issue async K DMA (block-shared K tile) ----
#pragma unroll
        for (int i = 0; i < 4; ++i)
            async_lds16(gk_base + (size_t)(kv0 + i * 8) * QKV_N, lk_base + i * 512);

        // ---- V global loads (latency overlaps K DMA) ----
        const __bf16* vp = vsrc + (size_t)(kv0 + vkey) * QKV_N;
        uint4 va0 = *(const uint4*)(vp);
        uint4 va1 = *(const uint4*)(vp + 8);
        uint4 vb0 = *(const uint4*)(vp + QKV_N);
        uint4 vb1 = *(const uint4*)(vp + QKV_N + 8);

        {
            const unsigned short* a0 = (const unsigned short*)&va0;
            const unsigned short* a1 = (const unsigned short*)&va1;
            const unsigned short* b0_ = (const unsigned short*)&vb0;
            const unsigned short* b1_ = (const unsigned short*)&vb1;
#pragma unroll
            for (int j = 0; j < 8; ++j) {
                *(uint32_t*)&vT[vdg + j][vkey] = (uint32_t)a0[j] | ((uint32_t)b0_[j] << 16);
                *(uint32_t*)&vT[vdg + 8 + j][vkey] = (uint32_t)a1[j] | ((uint32_t)b1_[j] << 16);
            }
        }
        __syncthreads();          // drains K DMA (vmcnt) + vT visible

#pragma unroll
        for (int qs = 0; qs < 2; ++qs) {
            micro_pass(kv0, 0, qs);
            // micro 1 valid iff kv0 < qsub0 (skip fully-masked micro on sub0 diag tile)
            if (kv0 < q0 + qs * 64)
                micro_pass(kv0 + 64, 1, qs);
        }
        __syncthreads();          // all Kls/vT reads done before next tile's staging
    }

    // ---- epilogue ----
    const size_t blk = ((size_t)b * 16 + gp) * 40 + xr;
    const size_t pb = blk * (size_t)(2 * 128 * 64);
#pragma unroll
    for (int qs = 0; qs < 2; ++qs)
#pragma unroll
        for (int h = 0; h < 2; ++h) {
            float lt = l_st[qs][h];
            lt += __shfl_xor(lt, 16);
            lt += __shfl_xor(lt, 32);
            const float inv = 1.f / lt;
            __half* prowO = partO + pb + (size_t)(h * 128 + qs * 64 + qr16) * 64 + quad * 4;
#pragma unroll
            for (int dt = 0; dt < 4; ++dt) {
                __half ob[4];
#pragma unroll
                for (int r = 0; r < 4; ++r) ob[r] = __float2half(o[qs][h][dt][r] * inv);
                *(uint2*)(prowO + dt * 16) = *(const uint2*)ob;
            }
            if (quad == 0)
                partL[blk * 256 + h * 128 + qs * 64 + qr16] = lt;
        }
}

// ---------------- combine partial chunks -> attnb (bf16) ----------------
__global__ __launch_bounds__(256, 4)
void k_combine(const __half* __restrict__ partO, const float* __restrict__ partL,
               __bf16* __restrict__ attnb) {
    const int qh = blockIdx.x, gp = blockIdx.y, b = blockIdx.z;
    const int qi = qh >> 1, h = qh & 1;
    const int nc = (qi >> 2) + 1;
    int x0;
    if (qi < 4) x0 = qi;
    else if (qi < 8) x0 = 4 + (qi - 4) * 2;
    else if (qi < 12) x0 = 12 + (qi - 8) * 3;
    else x0 = 24 + (qi - 12) * 4;

    const int t = threadIdx.x;
    const int row = t >> 1, half = t & 1;   // row = q 0..127
    const int d0 = half * 32;
    const size_t gbase = ((size_t)b * 16 + gp) * 40;

    float W = 0.f;
    float acc[32];
#pragma unroll
    for (int i = 0; i < 32; ++i) acc[i] = 0.f;
    for (int cc = 0; cc < nc; ++cc) {
        const float a = partL[(gbase + x0 + cc) * 256 + h * 128 + row];
        W += a;
        const __half* src = partO + (gbase + x0 + cc) * (size_t)(2 * 128 * 64) +
                            (size_t)(h * 128 + row) * 64 + d0;
#pragma unroll
        for (int i = 0; i < 32; i += 8) {
            uint4 u = *(const uint4*)(src + i);
            const __half* hs = (const __half*)&u;
#pragma unroll
            for (int j = 0; j < 8; ++j) acc[i + j] += a * __half2float(hs[j]);
        }
    }
    const float inv = 1.f / W;
    const int h_abs = (gp >> 1) * 4 + (gp & 1) * 2 + h;
    __bf16* dst = attnb + ((size_t)b * S_LEN + qi * 128 + row) * E_DIM + h_abs * 64 + d0;
#pragma unroll
    for (int i = 0; i < 32; i += 8) {
        __bf16 ob[8];
#pragma unroll
        for (int j = 0; j < 8; ++j) ob[j] = (__bf16)(acc[i + j] * inv);
        *(uint4*)(dst + i) = *(const uint4*)ob;
    }
}

// ---------------- launch ----------------
extern "C" void kernel_launch(void* const* d_in, const int* in_sizes, int n_in,
                              void* d_out, int out_size, void* d_ws, size_t ws_size,
                              hipStream_t stream) {
    const float* x  = (const float*)d_in[0];
    const float* Wq = (const float*)d_in[1];
    const float* Wk = (const float*)d_in[2];
    const float* Wv = (const float*)d_in[3];
    const float* Wo = (const float*)d_in[4];
    const float* bo = (const float*)d_in[5];

    __bf16* xb    = (__bf16*)d_ws;                         // [4096][2048]
    __bf16* WtAll = xb + (size_t)M_ROWS * E_DIM;           // [3072][2048]
    __bf16* WoT   = WtAll + (size_t)QKV_N * E_DIM;         // [2048][2048]
    __bf16* qkv   = WoT + (size_t)E_DIM * E_DIM;           // [4096][3072]
    __bf16* attnb = qkv + (size_t)M_ROWS * QKV_N;          // [4096][2048]
    __half* partO = (__half*)(attnb + (size_t)M_ROWS * E_DIM);    // [1280][2*128*64]
    float* partL  = (float*)(partO + (size_t)1280 * 2 * 128 * 64); // [1280][256]

    k_convert<<<(M_ROWS * E_DIM / 4 + 255) / 256, 256, 0, stream>>>(x, xb, M_ROWS * E_DIM);
    k_transpose_all<<<dim3(64, 64, 4), dim3(32, 8), 0, stream>>>(Wq, Wk, Wv, Wo, WtAll, WoT);

    k_gemm8<<<dim3((M_ROWS / 256) * (QKV_N / 256)), 512, 0, stream>>>(
        xb, WtAll, qkv, M_ROWS, QKV_N, E_DIM);

    k_attn<<<dim3(40, 16, 2), 256, 0, stream>>>(qkv, partO, partL);
    k_combine<<<dim3(32, 16, 2), 256, 0, stream>>>(partO, partL, attnb);

    k_gemm_bt<1><<<dim3(E_DIM / 128, M_ROWS / 128), 256, 0, stream>>>(
        attnb, WoT, d_out, bo, M_ROWS, E_DIM, E_DIM);
}

// Round 6
// 328.719 us; speedup vs baseline: 1.2125x; 1.2125x over previous
//
#include <hip/hip_runtime.h>
#include <hip/hip_fp16.h>

#define E_DIM 2048
#define S_LEN 2048
#define NH 32
#define HD 64
#define KV_DIM 512
#define QKV_N 3072      // E + 2*KV
#define M_ROWS 4096     // B*S
#define QK_SCALE 0.18033688011112042f  // (1/sqrt(64)) * log2(e)

typedef __bf16 bf16x8 __attribute__((ext_vector_type(8)));
typedef float f32x4 __attribute__((ext_vector_type(4)));

__device__ __forceinline__ void async_lds16(const __bf16* g, __bf16* l) {
    __builtin_amdgcn_global_load_lds(
        (const __attribute__((address_space(1))) void*)g,
        (__attribute__((address_space(3))) void*)l, 16, 0, 0);
}

#define BAR() asm volatile("s_barrier" ::: "memory")

// ---------------- fp32 -> bf16 elementwise convert ----------------
__global__ void k_convert(const float* __restrict__ x, __bf16* __restrict__ xb, int n) {
    int i = (blockIdx.x * blockDim.x + threadIdx.x) * 4;
    if (i < n) {
        float4 v = *(const float4*)(x + i);
        xb[i + 0] = (__bf16)v.x;
        xb[i + 1] = (__bf16)v.y;
        xb[i + 2] = (__bf16)v.z;
        xb[i + 3] = (__bf16)v.w;
    }
}

// ---------------- all four weight transposes in one launch ----------------
__global__ void k_transpose_all(const float* __restrict__ Wq, const float* __restrict__ Wk,
                                const float* __restrict__ Wv, const float* __restrict__ Wo,
                                __bf16* __restrict__ WtAll, __bf16* __restrict__ WoT) {
    const int which = blockIdx.z;
    const float* W;
    __bf16* dst;
    int N;
    float scale = 1.f;
    if (which == 0)      { W = Wq; dst = WtAll;                                    N = E_DIM;  scale = QK_SCALE; }
    else if (which == 1) { W = Wk; dst = WtAll + (size_t)E_DIM * E_DIM;            N = KV_DIM; }
    else if (which == 2) { W = Wv; dst = WtAll + (size_t)(E_DIM + KV_DIM) * E_DIM; N = KV_DIM; }
    else                 { W = Wo; dst = WoT;                                      N = E_DIM;  }
    const int n0 = blockIdx.x * 32;
    if (n0 >= N) return;
    const int k0 = blockIdx.y * 32;
    __shared__ float tile[32][33];
    int tx = threadIdx.x, ty = threadIdx.y;
#pragma unroll
    for (int j = 0; j < 4; ++j)
        tile[ty + j * 8][tx] = W[(size_t)(k0 + ty + j * 8) * N + n0 + tx];
    __syncthreads();
#pragma unroll
    for (int j = 0; j < 4; ++j)
        dst[(size_t)(n0 + ty + j * 8) * E_DIM + k0 + tx] = (__bf16)(tile[tx][ty + j * 8] * scale);
}

// ---------------- 256x256 8-phase bf16 GEMM (QKV projection) ----------------
#define STG(g, l, bb, hh, kt) do {                                                              \
    async_lds16((g) + (size_t)((hh) * 128) * K + (size_t)(kt) * 64,                             \
                (l) + (bb) * 16384 + (hh) * 8192);                                              \
    async_lds16((g) + (size_t)((hh) * 128 + 64) * K + (size_t)(kt) * 64,                        \
                (l) + (bb) * 16384 + (hh) * 8192 + 4096);                                       \
} while (0)

#define LDA_(p, mq) do {                                                                        \
    _Pragma("unroll") for (int i_ = 0; i_ < 4; ++i_) {                                          \
        const char* rp_ = pAs + (p) * 32768 + ((mq) * 128 + rA + i_ * 16) * 128;                \
        a[i_][0] = *(const bf16x8*)(rp_ + swzk0);                                               \
        a[i_][1] = *(const bf16x8*)(rp_ + swzk1);                                               \
    }                                                                                           \
} while (0)

#define LDB_(p, nq, b) do {                                                                     \
    _Pragma("unroll") for (int j_ = 0; j_ < 2; ++j_) {                                          \
        const char* rp_ = pBs + (p) * 32768 + ((nq) * 128 + rB + j_ * 16) * 128;                \
        b[j_][0] = *(const bf16x8*)(rp_ + swzk0);                                               \
        b[j_][1] = *(const bf16x8*)(rp_ + swzk1);                                               \
    }                                                                                           \
} while (0)

#define MM(mq, nq, b) do {                                                                      \
    __builtin_amdgcn_s_setprio(1);                                                              \
    _Pragma("unroll") for (int i_ = 0; i_ < 4; ++i_)                                            \
    _Pragma("unroll") for (int j_ = 0; j_ < 2; ++j_) {                                          \
        acc[mq][nq][i_][j_] = __builtin_amdgcn_mfma_f32_16x16x32_bf16(                          \
            a[i_][0], b[j_][0], acc[mq][nq][i_][j_], 0, 0, 0);                                  \
        acc[mq][nq][i_][j_] = __builtin_amdgcn_mfma_f32_16x16x32_bf16(                          \
            a[i_][1], b[j_][1], acc[mq][nq][i_][j_], 0, 0, 0);                                  \
    }                                                                                           \
    __builtin_amdgcn_s_setprio(0);                                                              \
} while (0)

#define GROUP(p, kt, S1, S2, WAITSTMT) do {                                                     \
    LDA_(p, 0);                                                                                 \
    LDB_(p, 0, b0);                                                                             \
    if (S1) STG(gA, lA, (p) ^ 1, 1, (kt) + 1);                                                  \
    BAR(); MM(0, 0, b0); BAR();                                                                 \
    LDB_(p, 1, b1);                                                                             \
    if (S2) STG(gA, lA, (p), 0, (kt) + 2);                                                      \
    BAR(); MM(0, 1, b1); BAR();                                                                 \
    LDA_(p, 1);                                                                                 \
    if (S2) STG(gB, lB, (p), 0, (kt) + 2);                                                      \
    BAR(); MM(1, 1, b1); BAR();                                                                 \
    if (S2) STG(gB, lB, (p), 1, (kt) + 2);                                                      \
    WAITSTMT;                                                                                   \
    BAR(); MM(1, 0, b0); BAR();                                                                 \
} while (0)

__global__ __launch_bounds__(512, 2)
void k_gemm8(const __bf16* __restrict__ A, const __bf16* __restrict__ Bt,
             __bf16* __restrict__ C, int M, int N, int K) {
    __shared__ __attribute__((aligned(16))) __bf16 As[2][16384];
    __shared__ __attribute__((aligned(16))) __bf16 Bs[2][16384];
    const int T = K >> 6;              // K-tiles of 64; requires T >= 3
    const int nbx = N >> 8;
    const int bid = blockIdx.x;
    const int swz = (bid & 7) * ((int)gridDim.x >> 3) + (bid >> 3);
    const int m0 = (swz / nbx) << 8;
    const int n0 = (swz % nbx) << 8;

    const int t = threadIdx.x;
    const int lane = t & 63, w = t >> 6;
    const int quad = lane >> 4, l16 = lane & 15;
    const int wr = w >> 2, wc = w & 3;

    const int rbase = w * 8 + (lane >> 3);
    const int cswz = ((lane & 7) ^ (lane >> 3)) * 8;
    const __bf16* gA = A + (size_t)(m0 + rbase) * K + cswz;
    const __bf16* gB = Bt + (size_t)(n0 + rbase) * K + cswz;
    __bf16* lA = &As[0][0] + w * 512;
    __bf16* lB = &Bs[0][0] + w * 512;

    const int swzk0 = ((0 + quad) ^ (l16 & 7)) * 16;
    const int swzk1 = ((4 + quad) ^ (l16 & 7)) * 16;
    const int rA = wr * 64 + l16;
    const int rB = wc * 32 + l16;
    const char* pAs = (const char*)&As[0][0];
    const char* pBs = (const char*)&Bs[0][0];

    f32x4 acc[2][2][4][2] = {};
    bf16x8 a[4][2], b0[2][2], b1[2][2];

    STG(gA, lA, 0, 0, 0); STG(gA, lA, 0, 1, 0);
    STG(gB, lB, 0, 0, 0); STG(gB, lB, 0, 1, 0);
    STG(gA, lA, 1, 0, 1);
    STG(gB, lB, 1, 0, 1); STG(gB, lB, 1, 1, 1);
    asm volatile("s_waitcnt vmcnt(6)" ::: "memory");
    BAR();

    int p = 0;
    for (int kt = 0; kt < T - 2; ++kt) {
        GROUP(p, kt, 1, 1, asm volatile("s_waitcnt vmcnt(6)" ::: "memory"));
        p ^= 1;
    }
    GROUP(p, T - 2, 1, 0, asm volatile("s_waitcnt vmcnt(0)" ::: "memory"));
    p ^= 1;
    GROUP(p, T - 1, 0, 0, (void)0);

#pragma unroll
    for (int mq = 0; mq < 2; ++mq)
#pragma unroll
        for (int nq = 0; nq < 2; ++nq)
#pragma unroll
            for (int i = 0; i < 4; ++i)
#pragma unroll
                for (int j = 0; j < 2; ++j) {
                    const int row = m0 + mq * 128 + wr * 64 + i * 16 + quad * 4;
                    const int col = n0 + nq * 128 + wc * 32 + j * 16 + l16;
#pragma unroll
                    for (int r = 0; r < 4; ++r)
                        C[(size_t)(row + r) * N + col] = (__bf16)acc[mq][nq][i][j][r];
                }
    (void)M;
}

// ---------------- bf16 MFMA GEMM, BK=64 per barrier round (O-projection) ----------------
template <int OUT_F32>
__global__ __launch_bounds__(256, 2)
void k_gemm_bt(const __bf16* __restrict__ A, const __bf16* __restrict__ Bt,
               void* __restrict__ Cout, const float* __restrict__ bias,
               int M, int N, int K) {
    __shared__ __attribute__((aligned(16))) __bf16 As2[128 * 64];
    __shared__ __attribute__((aligned(16))) __bf16 Bs2[128 * 64];
    const int t = threadIdx.x;
    const int lane = t & 63, wave = t >> 6;
    const int quad = lane >> 4, l16 = lane & 15;
    const int wr = wave >> 1, wc = wave & 1;
    const int m0 = blockIdx.y * 128, n0 = blockIdx.x * 128;

    const int srow = t >> 2;
    const int sblk = (t & 3) ^ ((t >> 3) & 3);
    const __bf16* gA0 = A + (size_t)(m0 + srow) * K + sblk * 8;
    const __bf16* gA1 = gA0 + (size_t)64 * K;
    const __bf16* gB0 = Bt + (size_t)(n0 + srow) * K + sblk * 8;
    const __bf16* gB1 = gB0 + (size_t)64 * K;

    f32x4 acc[4][4] = {};

    for (int k0 = 0; k0 < K; k0 += 64) {
#pragma unroll
        for (int ks = 0; ks < 2; ++ks) {
            async_lds16(gA0 + k0 + ks * 32, As2 + ks * 4096 + wave * 512);
            async_lds16(gA1 + k0 + ks * 32, As2 + ks * 4096 + 2048 + wave * 512);
            async_lds16(gB0 + k0 + ks * 32, Bs2 + ks * 4096 + wave * 512);
            async_lds16(gB1 + k0 + ks * 32, Bs2 + ks * 4096 + 2048 + wave * 512);
        }
        __syncthreads();
#pragma unroll
        for (int ks = 0; ks < 2; ++ks) {
            bf16x8 af[4], bfr[4];
#pragma unroll
            for (int i = 0; i < 4; ++i) {
                const int row = wr * 64 + i * 16 + l16;
                af[i] = *(const bf16x8*)((const char*)As2 + ks * 8192 + row * 64 +
                                         ((quad ^ ((row >> 1) & 3)) * 16));
            }
#pragma unroll
            for (int j = 0; j < 4; ++j) {
                const int row = wc * 64 + j * 16 + l16;
                bfr[j] = *(const bf16x8*)((const char*)Bs2 + ks * 8192 + row * 64 +
                                          ((quad ^ ((row >> 1) & 3)) * 16));
            }
#pragma unroll
            for (int i = 0; i < 4; ++i)
#pragma unroll
                for (int j = 0; j < 4; ++j)
                    acc[i][j] = __builtin_amdgcn_mfma_f32_16x16x32_bf16(af[i], bfr[j], acc[i][j], 0, 0, 0);
        }
        __syncthreads();
    }

#pragma unroll
    for (int i = 0; i < 4; ++i)
#pragma unroll
        for (int j = 0; j < 4; ++j) {
            const int row = m0 + wr * 64 + i * 16 + quad * 4;
            const int col = n0 + wc * 64 + j * 16 + l16;
#pragma unroll
            for (int r = 0; r < 4; ++r) {
                float v = acc[i][j][r];
                if (OUT_F32) ((float*)Cout)[(size_t)(row + r) * N + col] = v + bias[col];
                else ((__bf16*)Cout)[(size_t)(row + r) * N + col] = (__bf16)v;
            }
        }
}

// ---------------- KV-split flash attention, 128-query blocks ----------------
// Round-5 failure: __launch_bounds__(256,3) capped VGPR at ~170 < ~190 needed ->
// accumulator spill to scratch (VGPR_Count 84, WRITE_SIZE 243 MB). Fix:
// (a) __launch_bounds__(256,2) -> 256-VGPR cap, no spill (2 blocks/CU, VGPR-bound);
// (b) MICRO as macro: qs/m are textual constants -> no runtime-indexed arrays.
#define MICRO(kb, mm, qs) do {                                                                  \
    const int qsub0_ = q0 + (qs) * 64;                                                          \
    const int qrow_ = qsub0_ + qr16;                                                            \
    const bool diag_ = ((kb) == qsub0_);                                                        \
    f32x4 sA_[4], sB_[4];                                                                       \
    __builtin_amdgcn_s_setprio(1);                                                              \
    _Pragma("unroll") for (int kt_ = 0; kt_ < 4; ++kt_) {                                       \
        const int kr_ = (mm) * 64 + kt_ * 16 + l16;                                             \
        const char* kb__ = (const char*)Kls + kr_ * 128;                                        \
        bf16x8 kf0_ = *(const bf16x8*)(kb__ + ((quad ^ (kr_ & 7)) * 16));                       \
        bf16x8 kf1_ = *(const bf16x8*)(kb__ + (((4 + quad) ^ (kr_ & 7)) * 16));                 \
        f32x4 z_ = {};                                                                          \
        z_ = __builtin_amdgcn_mfma_f32_16x16x32_bf16(kf0_, qf[qs][0][0], z_, 0, 0, 0);          \
        sA_[kt_] = __builtin_amdgcn_mfma_f32_16x16x32_bf16(kf1_, qf[qs][0][1], z_, 0, 0, 0);    \
        f32x4 w_ = {};                                                                          \
        w_ = __builtin_amdgcn_mfma_f32_16x16x32_bf16(kf0_, qf[qs][1][0], w_, 0, 0, 0);          \
        sB_[kt_] = __builtin_amdgcn_mfma_f32_16x16x32_bf16(kf1_, qf[qs][1][1], w_, 0, 0, 0);    \
    }                                                                                           \
    __builtin_amdgcn_s_setprio(0);                                                              \
    _Pragma("unroll") for (int hf_ = 0; hf_ < 2; ++hf_) {                                       \
        bf16x8 vf_[4];                                                                          \
        const int koff_ = (mm) * 64 + hf_ * 32;                                                 \
        _Pragma("unroll") for (int cc_ = 0; cc_ < 4; ++cc_)                                     \
            vf_[cc_] = *(const bf16x8*)&vT[cc_ * 16 + l16][koff_ + quad * 8];                   \
        _Pragma("unroll") for (int h_ = 0; h_ < 2; ++h_) {                                      \
            char* prow_ = (char*)&pT[wave][h_][0] + l16 * 64;                                   \
            float lsum_ = 0.f;                                                                  \
            _Pragma("unroll") for (int u_ = 0; u_ < 2; ++u_) {                                  \
                const int kt_ = 2 * hf_ + u_;                                                   \
                f32x4 pv_;                                                                      \
                _Pragma("unroll") for (int r_ = 0; r_ < 4; ++r_)                                \
                    pv_[r_] = exp2f(h_ ? sB_[kt_][r_] : sA_[kt_][r_]);                          \
                if (diag_) {                                                                    \
                    const int kbase_ = (kb) + kt_ * 16 + quad * 4;                              \
                    _Pragma("unroll") for (int r_ = 0; r_ < 4; ++r_)                            \
                        if (kbase_ + r_ > qrow_) pv_[r_] = 0.f;                                 \
                }                                                                               \
                _Pragma("unroll") for (int r_ = 0; r_ < 4; ++r_) lsum_ += pv_[r_];              \
                __bf16 pb_[4];                                                                  \
                _Pragma("unroll") for (int r_ = 0; r_ < 4; ++r_) pb_[r_] = (__bf16)pv_[r_];     \
                const int bi_ = (2 * u_ + (quad >> 1)) ^ pswz;                                  \
                *(uint2*)(prow_ + bi_ * 16 + (quad & 1) * 8) = *(const uint2*)pb_;              \
            }                                                                                   \
            l_st[qs][h_] += lsum_;                                                              \
            bf16x8 pf_ = *(const bf16x8*)(prow_ + ((quad ^ pswz) * 16));                        \
            __builtin_amdgcn_s_setprio(1);                                                      \
            _Pragma("unroll") for (int cc_ = 0; cc_ < 4; ++cc_)                                 \
                o[qs][h_][cc_] = __builtin_amdgcn_mfma_f32_16x16x32_bf16(                       \
                    vf_[cc_], pf_, o[qs][h_][cc_], 0, 0, 0);                                    \
            __builtin_amdgcn_s_setprio(0);                                                      \
        }                                                                                       \
    }                                                                                           \
} while (0)

__global__ __launch_bounds__(256, 2)
void k_attn(const __bf16* __restrict__ qkv, __half* __restrict__ partO,
            float* __restrict__ partL) {
    const int xr = (int)(gridDim.x - 1 - blockIdx.x);   // reversed: biggest blocks first
    int qi, c;
    if (xr < 4)       { qi = xr;                   c = 0; }
    else if (xr < 12) { qi = 4 + ((xr - 4) >> 1);  c = (xr - 4) & 1; }
    else if (xr < 24) { qi = 8 + (xr - 12) / 3;    c = (xr - 12) % 3; }
    else              { qi = 12 + ((xr - 24) >> 2); c = (xr - 24) & 3; }
    const int q0 = qi * 128;
    const int k_lo = c * 512;
    const int k_hi = min(k_lo + 512, q0 + 128);

    const int gp = blockIdx.y;
    const int g = gp >> 1;
    const int h0 = g * 4 + (gp & 1) * 2;
    const int b = blockIdx.z;
    const int t = threadIdx.x;
    const int lane = t & 63, wave = t >> 6;
    const int quad = lane >> 4, l16 = lane & 15;

    __shared__ __attribute__((aligned(16))) __bf16 Kls[128 * 64];   // [key][d], swizzled
    __shared__ __attribute__((aligned(16))) __bf16 vT[64][136];     // [d][key 0..127], padded
    __shared__ __attribute__((aligned(16))) __bf16 pT[4][2][512];   // per-wave, per-head P^T

    const __bf16* base = qkv + (size_t)b * S_LEN * QKV_N;
    const int qr16 = wave * 16 + l16;   // per-sub query row offset within 64

    // Q fragments for both sub-blocks, both heads
    bf16x8 qf[2][2][2];
#pragma unroll
    for (int qs = 0; qs < 2; ++qs)
#pragma unroll
        for (int h = 0; h < 2; ++h)
#pragma unroll
            for (int s = 0; s < 2; ++s)
                qf[qs][h][s] = *(const bf16x8*)(base + (size_t)(q0 + qs * 64 + qr16) * QKV_N +
                                                (h0 + h) * HD + s * 32 + quad * 8);

    f32x4 o[2][2][4] = {};          // [qs][h][cc]
    float l_st[2][2] = {};

    const int vkey = lane * 2, vdg = wave * 16;
    const __bf16* vsrc = base + (E_DIM + KV_DIM) + g * HD + vdg;
    const __bf16* ksrc = base + E_DIM + g * HD;

    const int klocal = lane >> 3;
    const int kdblk = (lane & 7) ^ (klocal & 7);
    const __bf16* gk_base = ksrc + (size_t)(wave * 32 + klocal) * QKV_N + kdblk * 8;
    __bf16* lk_base = Kls + wave * 2048;

    const int pswz = (l16 >> 1) & 3;

    for (int kv0 = k_lo; kv0 < k_hi; kv0 += 128) {
        // ---- issue async K DMA (block-shared K tile) ----
#pragma unroll
        for (int i = 0; i < 4; ++i)
            async_lds16(gk_base + (size_t)(kv0 + i * 8) * QKV_N, lk_base + i * 512);

        // ---- V global loads (latency overlaps K DMA) ----
        const __bf16* vp = vsrc + (size_t)(kv0 + vkey) * QKV_N;
        uint4 va0 = *(const uint4*)(vp);
        uint4 va1 = *(const uint4*)(vp + 8);
        uint4 vb0 = *(const uint4*)(vp + QKV_N);
        uint4 vb1 = *(const uint4*)(vp + QKV_N + 8);

        {
            const unsigned short* a0 = (const unsigned short*)&va0;
            const unsigned short* a1 = (const unsigned short*)&va1;
            const unsigned short* b0_ = (const unsigned short*)&vb0;
            const unsigned short* b1_ = (const unsigned short*)&vb1;
#pragma unroll
            for (int j = 0; j < 8; ++j) {
                *(uint32_t*)&vT[vdg + j][vkey] = (uint32_t)a0[j] | ((uint32_t)b0_[j] << 16);
                *(uint32_t*)&vT[vdg + 8 + j][vkey] = (uint32_t)a1[j] | ((uint32_t)b1_[j] << 16);
            }
        }
        __syncthreads();          // drains K DMA (vmcnt) + vT visible

        // sub-block 0
        MICRO(kv0, 0, 0);
        if (kv0 < q0)
            MICRO(kv0 + 64, 1, 0);
        // sub-block 1
        MICRO(kv0, 0, 1);
        if (kv0 < q0 + 64)
            MICRO(kv0 + 64, 1, 1);

        __syncthreads();          // all Kls/vT reads done before next tile's staging
    }

    // ---- epilogue ----
    const size_t blk = ((size_t)b * 16 + gp) * 40 + xr;
    const size_t pb = blk * (size_t)(2 * 128 * 64);
#pragma unroll
    for (int qs = 0; qs < 2; ++qs)
#pragma unroll
        for (int h = 0; h < 2; ++h) {
            float lt = l_st[qs][h];
            lt += __shfl_xor(lt, 16);
            lt += __shfl_xor(lt, 32);
            const float inv = 1.f / lt;
            __half* prowO = partO + pb + (size_t)(h * 128 + qs * 64 + qr16) * 64 + quad * 4;
#pragma unroll
            for (int dt = 0; dt < 4; ++dt) {
                __half ob[4];
#pragma unroll
                for (int r = 0; r < 4; ++r) ob[r] = __float2half(o[qs][h][dt][r] * inv);
                *(uint2*)(prowO + dt * 16) = *(const uint2*)ob;
            }
            if (quad == 0)
                partL[blk * 256 + h * 128 + qs * 64 + qr16] = lt;
        }
}

// ---------------- combine partial chunks -> attnb (bf16) ----------------
__global__ __launch_bounds__(256, 4)
void k_combine(const __half* __restrict__ partO, const float* __restrict__ partL,
               __bf16* __restrict__ attnb) {
    const int qh = blockIdx.x, gp = blockIdx.y, b = blockIdx.z;
    const int qi = qh >> 1, h = qh & 1;
    const int nc = (qi >> 2) + 1;
    int x0;
    if (qi < 4) x0 = qi;
    else if (qi < 8) x0 = 4 + (qi - 4) * 2;
    else if (qi < 12) x0 = 12 + (qi - 8) * 3;
    else x0 = 24 + (qi - 12) * 4;

    const int t = threadIdx.x;
    const int row = t >> 1, half = t & 1;   // row = q 0..127
    const int d0 = half * 32;
    const size_t gbase = ((size_t)b * 16 + gp) * 40;

    float W = 0.f;
    float acc[32];
#pragma unroll
    for (int i = 0; i < 32; ++i) acc[i] = 0.f;
    for (int cc = 0; cc < nc; ++cc) {
        const float a = partL[(gbase + x0 + cc) * 256 + h * 128 + row];
        W += a;
        const __half* src = partO + (gbase + x0 + cc) * (size_t)(2 * 128 * 64) +
                            (size_t)(h * 128 + row) * 64 + d0;
#pragma unroll
        for (int i = 0; i < 32; i += 8) {
            uint4 u = *(const uint4*)(src + i);
            const __half* hs = (const __half*)&u;
#pragma unroll
            for (int j = 0; j < 8; ++j) acc[i + j] += a * __half2float(hs[j]);
        }
    }
    const float inv = 1.f / W;
    const int h_abs = (gp >> 1) * 4 + (gp & 1) * 2 + h;
    __bf16* dst = attnb + ((size_t)b * S_LEN + qi * 128 + row) * E_DIM + h_abs * 64 + d0;
#pragma unroll
    for (int i = 0; i < 32; i += 8) {
        __bf16 ob[8];
#pragma unroll
        for (int j = 0; j < 8; ++j) ob[j] = (__bf16)(acc[i + j] * inv);
        *(uint4*)(dst + i) = *(const uint4*)ob;
    }
}

// ---------------- launch ----------------
extern "C" void kernel_launch(void* const* d_in, const int* in_sizes, int n_in,
                              void* d_out, int out_size, void* d_ws, size_t ws_size,
                              hipStream_t stream) {
    const float* x  = (const float*)d_in[0];
    const float* Wq = (const float*)d_in[1];
    const float* Wk = (const float*)d_in[2];
    const float* Wv = (const float*)d_in[3];
    const float* Wo = (const float*)d_in[4];
    const float* bo = (const float*)d_in[5];

    __bf16* xb    = (__bf16*)d_ws;                         // [4096][2048]
    __bf16* WtAll = xb + (size_t)M_ROWS * E_DIM;           // [3072][2048]
    __bf16* WoT   = WtAll + (size_t)QKV_N * E_DIM;         // [2048][2048]
    __bf16* qkv   = WoT + (size_t)E_DIM * E_DIM;           // [4096][3072]
    __bf16* attnb = qkv + (size_t)M_ROWS * QKV_N;          // [4096][2048]
    __half* partO = (__half*)(attnb + (size_t)M_ROWS * E_DIM);    // [1280][2*128*64]
    float* partL  = (float*)(partO + (size_t)1280 * 2 * 128 * 64); // [1280][256]

    k_convert<<<(M_ROWS * E_DIM / 4 + 255) / 256, 256, 0, stream>>>(x, xb, M_ROWS * E_DIM);
    k_transpose_all<<<dim3(64, 64, 4), dim3(32, 8), 0, stream>>>(Wq, Wk, Wv, Wo, WtAll, WoT);

    k_gemm8<<<dim3((M_ROWS / 256) * (QKV_N / 256)), 512, 0, stream>>>(
        xb, WtAll, qkv, M_ROWS, QKV_N, E_DIM);

    k_attn<<<dim3(40, 16, 2), 256, 0, stream>>>(qkv, partO, partL);
    k_combine<<<dim3(32, 16, 2), 256, 0, stream>>>(partO, partL, attnb);

    k_gemm_bt<1><<<dim3(E_DIM / 128, M_ROWS / 128), 256, 0, stream>>>(
        attnb, WoT, d_out, bo, M_ROWS, E_DIM, E_DIM);
}

// Round 7
// 327.431 us; speedup vs baseline: 1.2173x; 1.0039x over previous
//
#include <hip/hip_runtime.h>
#include <hip/hip_fp16.h>

#define E_DIM 2048
#define S_LEN 2048
#define NH 32
#define HD 64
#define KV_DIM 512
#define QKV_N 3072      // E + 2*KV
#define M_ROWS 4096     // B*S
#define QK_SCALE 0.18033688011112042f  // (1/sqrt(64)) * log2(e)

typedef __bf16 bf16x8 __attribute__((ext_vector_type(8)));
typedef __bf16 bf16x4 __attribute__((ext_vector_type(4)));
typedef float f32x4 __attribute__((ext_vector_type(4)));

__device__ __forceinline__ void async_lds16(const __bf16* g, __bf16* l) {
    __builtin_amdgcn_global_load_lds(
        (const __attribute__((address_space(1))) void*)g,
        (__attribute__((address_space(3))) void*)l, 16, 0, 0);
}

// 16x16x16 bf16 MFMA via inline asm (instruction exists on gfx950, ISA sec 10).
// B-frag k = quad*4+j  == QK C-layout granule -> P feeds PV directly, no LDS trip.
// s_nop 1 guards VALU-write -> MFMA-read hazard on cvt-produced operands.
__device__ __forceinline__ f32x4 mfma16(bf16x4 a, bf16x4 b, f32x4 c) {
    asm("s_nop 1\n\tv_mfma_f32_16x16x16_bf16 %0, %1, %2, %0"
        : "+v"(c) : "v"(a), "v"(b));
    return c;
}

#define BAR() asm volatile("s_barrier" ::: "memory")

// ---------------- fp32 -> bf16 elementwise convert ----------------
__global__ void k_convert(const float* __restrict__ x, __bf16* __restrict__ xb, int n) {
    int i = (blockIdx.x * blockDim.x + threadIdx.x) * 4;
    if (i < n) {
        float4 v = *(const float4*)(x + i);
        xb[i + 0] = (__bf16)v.x;
        xb[i + 1] = (__bf16)v.y;
        xb[i + 2] = (__bf16)v.z;
        xb[i + 3] = (__bf16)v.w;
    }
}

// ---------------- all four weight transposes in one launch ----------------
__global__ void k_transpose_all(const float* __restrict__ Wq, const float* __restrict__ Wk,
                                const float* __restrict__ Wv, const float* __restrict__ Wo,
                                __bf16* __restrict__ WtAll, __bf16* __restrict__ WoT) {
    const int which = blockIdx.z;
    const float* W;
    __bf16* dst;
    int N;
    float scale = 1.f;
    if (which == 0)      { W = Wq; dst = WtAll;                                    N = E_DIM;  scale = QK_SCALE; }
    else if (which == 1) { W = Wk; dst = WtAll + (size_t)E_DIM * E_DIM;            N = KV_DIM; }
    else if (which == 2) { W = Wv; dst = WtAll + (size_t)(E_DIM + KV_DIM) * E_DIM; N = KV_DIM; }
    else                 { W = Wo; dst = WoT;                                      N = E_DIM;  }
    const int n0 = blockIdx.x * 32;
    if (n0 >= N) return;
    const int k0 = blockIdx.y * 32;
    __shared__ float tile[32][33];
    int tx = threadIdx.x, ty = threadIdx.y;
#pragma unroll
    for (int j = 0; j < 4; ++j)
        tile[ty + j * 8][tx] = W[(size_t)(k0 + ty + j * 8) * N + n0 + tx];
    __syncthreads();
#pragma unroll
    for (int j = 0; j < 4; ++j)
        dst[(size_t)(n0 + ty + j * 8) * E_DIM + k0 + tx] = (__bf16)(tile[tx][ty + j * 8] * scale);
}

// ---------------- 256x256 8-phase bf16 GEMM (QKV projection) ----------------
#define STG(g, l, bb, hh, kt) do {                                                              \
    async_lds16((g) + (size_t)((hh) * 128) * K + (size_t)(kt) * 64,                             \
                (l) + (bb) * 16384 + (hh) * 8192);                                              \
    async_lds16((g) + (size_t)((hh) * 128 + 64) * K + (size_t)(kt) * 64,                        \
                (l) + (bb) * 16384 + (hh) * 8192 + 4096);                                       \
} while (0)

#define LDA_(p, mq) do {                                                                        \
    _Pragma("unroll") for (int i_ = 0; i_ < 4; ++i_) {                                          \
        const char* rp_ = pAs + (p) * 32768 + ((mq) * 128 + rA + i_ * 16) * 128;                \
        a[i_][0] = *(const bf16x8*)(rp_ + swzk0);                                               \
        a[i_][1] = *(const bf16x8*)(rp_ + swzk1);                                               \
    }                                                                                           \
} while (0)

#define LDB_(p, nq, b) do {                                                                     \
    _Pragma("unroll") for (int j_ = 0; j_ < 2; ++j_) {                                          \
        const char* rp_ = pBs + (p) * 32768 + ((nq) * 128 + rB + j_ * 16) * 128;                \
        b[j_][0] = *(const bf16x8*)(rp_ + swzk0);                                               \
        b[j_][1] = *(const bf16x8*)(rp_ + swzk1);                                               \
    }                                                                                           \
} while (0)

#define MM(mq, nq, b) do {                                                                      \
    __builtin_amdgcn_s_setprio(1);                                                              \
    _Pragma("unroll") for (int i_ = 0; i_ < 4; ++i_)                                            \
    _Pragma("unroll") for (int j_ = 0; j_ < 2; ++j_) {                                          \
        acc[mq][nq][i_][j_] = __builtin_amdgcn_mfma_f32_16x16x32_bf16(                          \
            a[i_][0], b[j_][0], acc[mq][nq][i_][j_], 0, 0, 0);                                  \
        acc[mq][nq][i_][j_] = __builtin_amdgcn_mfma_f32_16x16x32_bf16(                          \
            a[i_][1], b[j_][1], acc[mq][nq][i_][j_], 0, 0, 0);                                  \
    }                                                                                           \
    __builtin_amdgcn_s_setprio(0);                                                              \
} while (0)

#define GROUP(p, kt, S1, S2, WAITSTMT) do {                                                     \
    LDA_(p, 0);                                                                                 \
    LDB_(p, 0, b0);                                                                             \
    if (S1) STG(gA, lA, (p) ^ 1, 1, (kt) + 1);                                                  \
    BAR(); MM(0, 0, b0); BAR();                                                                 \
    LDB_(p, 1, b1);                                                                             \
    if (S2) STG(gA, lA, (p), 0, (kt) + 2);                                                      \
    BAR(); MM(0, 1, b1); BAR();                                                                 \
    LDA_(p, 1);                                                                                 \
    if (S2) STG(gB, lB, (p), 0, (kt) + 2);                                                      \
    BAR(); MM(1, 1, b1); BAR();                                                                 \
    if (S2) STG(gB, lB, (p), 1, (kt) + 2);                                                      \
    WAITSTMT;                                                                                   \
    BAR(); MM(1, 0, b0); BAR();                                                                 \
} while (0)

__global__ __launch_bounds__(512, 2)
void k_gemm8(const __bf16* __restrict__ A, const __bf16* __restrict__ Bt,
             __bf16* __restrict__ C, int M, int N, int K) {
    __shared__ __attribute__((aligned(16))) __bf16 As[2][16384];
    __shared__ __attribute__((aligned(16))) __bf16 Bs[2][16384];
    const int T = K >> 6;              // K-tiles of 64; requires T >= 3
    const int nbx = N >> 8;
    const int bid = blockIdx.x;
    const int swz = (bid & 7) * ((int)gridDim.x >> 3) + (bid >> 3);
    const int m0 = (swz / nbx) << 8;
    const int n0 = (swz % nbx) << 8;

    const int t = threadIdx.x;
    const int lane = t & 63, w = t >> 6;
    const int quad = lane >> 4, l16 = lane & 15;
    const int wr = w >> 2, wc = w & 3;

    const int rbase = w * 8 + (lane >> 3);
    const int cswz = ((lane & 7) ^ (lane >> 3)) * 8;
    const __bf16* gA = A + (size_t)(m0 + rbase) * K + cswz;
    const __bf16* gB = Bt + (size_t)(n0 + rbase) * K + cswz;
    __bf16* lA = &As[0][0] + w * 512;
    __bf16* lB = &Bs[0][0] + w * 512;

    const int swzk0 = ((0 + quad) ^ (l16 & 7)) * 16;
    const int swzk1 = ((4 + quad) ^ (l16 & 7)) * 16;
    const int rA = wr * 64 + l16;
    const int rB = wc * 32 + l16;
    const char* pAs = (const char*)&As[0][0];
    const char* pBs = (const char*)&Bs[0][0];

    f32x4 acc[2][2][4][2] = {};
    bf16x8 a[4][2], b0[2][2], b1[2][2];

    STG(gA, lA, 0, 0, 0); STG(gA, lA, 0, 1, 0);
    STG(gB, lB, 0, 0, 0); STG(gB, lB, 0, 1, 0);
    STG(gA, lA, 1, 0, 1);
    STG(gB, lB, 1, 0, 1); STG(gB, lB, 1, 1, 1);
    asm volatile("s_waitcnt vmcnt(6)" ::: "memory");
    BAR();

    int p = 0;
    for (int kt = 0; kt < T - 2; ++kt) {
        GROUP(p, kt, 1, 1, asm volatile("s_waitcnt vmcnt(6)" ::: "memory"));
        p ^= 1;
    }
    GROUP(p, T - 2, 1, 0, asm volatile("s_waitcnt vmcnt(0)" ::: "memory"));
    p ^= 1;
    GROUP(p, T - 1, 0, 0, (void)0);

#pragma unroll
    for (int mq = 0; mq < 2; ++mq)
#pragma unroll
        for (int nq = 0; nq < 2; ++nq)
#pragma unroll
            for (int i = 0; i < 4; ++i)
#pragma unroll
                for (int j = 0; j < 2; ++j) {
                    const int row = m0 + mq * 128 + wr * 64 + i * 16 + quad * 4;
                    const int col = n0 + nq * 128 + wc * 32 + j * 16 + l16;
#pragma unroll
                    for (int r = 0; r < 4; ++r)
                        C[(size_t)(row + r) * N + col] = (__bf16)acc[mq][nq][i][j][r];
                }
    (void)M;
}

// ---------------- bf16 MFMA GEMM, BK=64 per barrier round (O-projection) ----------------
template <int OUT_F32>
__global__ __launch_bounds__(256, 2)
void k_gemm_bt(const __bf16* __restrict__ A, const __bf16* __restrict__ Bt,
               void* __restrict__ Cout, const float* __restrict__ bias,
               int M, int N, int K) {
    __shared__ __attribute__((aligned(16))) __bf16 As2[128 * 64];
    __shared__ __attribute__((aligned(16))) __bf16 Bs2[128 * 64];
    const int t = threadIdx.x;
    const int lane = t & 63, wave = t >> 6;
    const int quad = lane >> 4, l16 = lane & 15;
    const int wr = wave >> 1, wc = wave & 1;
    const int m0 = blockIdx.y * 128, n0 = blockIdx.x * 128;

    const int srow = t >> 2;
    const int sblk = (t & 3) ^ ((t >> 3) & 3);
    const __bf16* gA0 = A + (size_t)(m0 + srow) * K + sblk * 8;
    const __bf16* gA1 = gA0 + (size_t)64 * K;
    const __bf16* gB0 = Bt + (size_t)(n0 + srow) * K + sblk * 8;
    const __bf16* gB1 = gB0 + (size_t)64 * K;

    f32x4 acc[4][4] = {};

    for (int k0 = 0; k0 < K; k0 += 64) {
#pragma unroll
        for (int ks = 0; ks < 2; ++ks) {
            async_lds16(gA0 + k0 + ks * 32, As2 + ks * 4096 + wave * 512);
            async_lds16(gA1 + k0 + ks * 32, As2 + ks * 4096 + 2048 + wave * 512);
            async_lds16(gB0 + k0 + ks * 32, Bs2 + ks * 4096 + wave * 512);
            async_lds16(gB1 + k0 + ks * 32, Bs2 + ks * 4096 + 2048 + wave * 512);
        }
        __syncthreads();
#pragma unroll
        for (int ks = 0; ks < 2; ++ks) {
            bf16x8 af[4], bfr[4];
#pragma unroll
            for (int i = 0; i < 4; ++i) {
                const int row = wr * 64 + i * 16 + l16;
                af[i] = *(const bf16x8*)((const char*)As2 + ks * 8192 + row * 64 +
                                         ((quad ^ ((row >> 1) & 3)) * 16));
            }
#pragma unroll
            for (int j = 0; j < 4; ++j) {
                const int row = wc * 64 + j * 16 + l16;
                bfr[j] = *(const bf16x8*)((const char*)Bs2 + ks * 8192 + row * 64 +
                                          ((quad ^ ((row >> 1) & 3)) * 16));
            }
#pragma unroll
            for (int i = 0; i < 4; ++i)
#pragma unroll
                for (int j = 0; j < 4; ++j)
                    acc[i][j] = __builtin_amdgcn_mfma_f32_16x16x32_bf16(af[i], bfr[j], acc[i][j], 0, 0, 0);
        }
        __syncthreads();
    }

#pragma unroll
    for (int i = 0; i < 4; ++i)
#pragma unroll
        for (int j = 0; j < 4; ++j) {
            const int row = m0 + wr * 64 + i * 16 + quad * 4;
            const int col = n0 + wc * 64 + j * 16 + l16;
#pragma unroll
            for (int r = 0; r < 4; ++r) {
                float v = acc[i][j][r];
                if (OUT_F32) ((float*)Cout)[(size_t)(row + r) * N + col] = v + bias[col];
                else ((__bf16*)Cout)[(size_t)(row + r) * N + col] = (__bf16)v;
            }
        }
}

// ---------------- KV-split flash attention, 128-query blocks ----------------
// P-path direct: PV uses v_mfma_f32_16x16x16_bf16 whose B-frag (k=quad*4+j) matches
// the QK output C-layout granule exactly -> exp'd scores feed PV in-register.
// pT LDS buffer + 8 ds_write + 4 ds_read + 2 lgkm waits per micro ELIMINATED.
// LDS = Kls 16K + vT 17.4K = 33792 B.
#define MICRO(kb, mm, qs) do {                                                                  \
    const int qsub0_ = q0 + (qs) * 64;                                                          \
    const int qrow_ = qsub0_ + qr16;                                                            \
    const bool diag_ = ((kb) == qsub0_);                                                        \
    f32x4 sA_[4], sB_[4];                                                                       \
    __builtin_amdgcn_s_setprio(1);                                                              \
    _Pragma("unroll") for (int kt_ = 0; kt_ < 4; ++kt_) {                                       \
        const int kr_ = (mm) * 64 + kt_ * 16 + l16;                                             \
        const char* kb__ = (const char*)Kls + kr_ * 128;                                        \
        bf16x8 kf0_ = *(const bf16x8*)(kb__ + ((quad ^ (kr_ & 7)) * 16));                       \
        bf16x8 kf1_ = *(const bf16x8*)(kb__ + (((4 + quad) ^ (kr_ & 7)) * 16));                 \
        f32x4 z_ = {};                                                                          \
        z_ = __builtin_amdgcn_mfma_f32_16x16x32_bf16(kf0_, qf[qs][0][0], z_, 0, 0, 0);          \
        sA_[kt_] = __builtin_amdgcn_mfma_f32_16x16x32_bf16(kf1_, qf[qs][0][1], z_, 0, 0, 0);    \
        f32x4 w_ = {};                                                                          \
        w_ = __builtin_amdgcn_mfma_f32_16x16x32_bf16(kf0_, qf[qs][1][0], w_, 0, 0, 0);          \
        sB_[kt_] = __builtin_amdgcn_mfma_f32_16x16x32_bf16(kf1_, qf[qs][1][1], w_, 0, 0, 0);    \
    }                                                                                           \
    __builtin_amdgcn_s_setprio(0);                                                              \
    _Pragma("unroll") for (int kt_ = 0; kt_ < 4; ++kt_) {                                       \
        bf16x4 v4_[4];                                                                          \
        const int koff_ = (mm) * 64 + kt_ * 16 + quad * 4;                                      \
        _Pragma("unroll") for (int cc_ = 0; cc_ < 4; ++cc_)                                     \
            v4_[cc_] = *(const bf16x4*)&vT[cc_ * 16 + l16][koff_];                              \
        _Pragma("unroll") for (int h_ = 0; h_ < 2; ++h_) {                                      \
            f32x4 sc_ = h_ ? sB_[kt_] : sA_[kt_];                                               \
            f32x4 p_;                                                                           \
            _Pragma("unroll") for (int r_ = 0; r_ < 4; ++r_) p_[r_] = exp2f(sc_[r_]);           \
            if (diag_) {                                                                        \
                const int kbase_ = (kb) + kt_ * 16 + quad * 4;                                  \
                _Pragma("unroll") for (int r_ = 0; r_ < 4; ++r_)                                \
                    if (kbase_ + r_ > qrow_) p_[r_] = 0.f;                                      \
            }                                                                                   \
            l_st[qs][h_] += p_[0] + p_[1] + p_[2] + p_[3];                                      \
            bf16x4 pb_;                                                                         \
            _Pragma("unroll") for (int r_ = 0; r_ < 4; ++r_) pb_[r_] = (__bf16)p_[r_];          \
            _Pragma("unroll") for (int cc_ = 0; cc_ < 4; ++cc_)                                 \
                o[qs][h_][cc_] = mfma16(v4_[cc_], pb_, o[qs][h_][cc_]);                         \
        }                                                                                       \
    }                                                                                           \
} while (0)

__global__ __launch_bounds__(256, 2)
void k_attn(const __bf16* __restrict__ qkv, __half* __restrict__ partO,
            float* __restrict__ partL) {
    const int xr = (int)(gridDim.x - 1 - blockIdx.x);   // reversed: biggest blocks first
    int qi, c;
    if (xr < 4)       { qi = xr;                   c = 0; }
    else if (xr < 12) { qi = 4 + ((xr - 4) >> 1);  c = (xr - 4) & 1; }
    else if (xr < 24) { qi = 8 + (xr - 12) / 3;    c = (xr - 12) % 3; }
    else              { qi = 12 + ((xr - 24) >> 2); c = (xr - 24) & 3; }
    const int q0 = qi * 128;
    const int k_lo = c * 512;
    const int k_hi = min(k_lo + 512, q0 + 128);

    const int gp = blockIdx.y;
    const int g = gp >> 1;
    const int h0 = g * 4 + (gp & 1) * 2;
    const int b = blockIdx.z;
    const int t = threadIdx.x;
    const int lane = t & 63, wave = t >> 6;
    const int quad = lane >> 4, l16 = lane & 15;

    __shared__ __attribute__((aligned(16))) __bf16 Kls[128 * 64];   // [key][d], swizzled
    __shared__ __attribute__((aligned(16))) __bf16 vT[64][136];     // [d][key 0..127], padded

    const __bf16* base = qkv + (size_t)b * S_LEN * QKV_N;
    const int qr16 = wave * 16 + l16;   // per-sub query row offset within 64

    // Q fragments for both sub-blocks, both heads
    bf16x8 qf[2][2][2];
#pragma unroll
    for (int qs = 0; qs < 2; ++qs)
#pragma unroll
        for (int h = 0; h < 2; ++h)
#pragma unroll
            for (int s = 0; s < 2; ++s)
                qf[qs][h][s] = *(const bf16x8*)(base + (size_t)(q0 + qs * 64 + qr16) * QKV_N +
                                                (h0 + h) * HD + s * 32 + quad * 8);

    f32x4 o[2][2][4] = {};          // [qs][h][cc]
    float l_st[2][2] = {};

    const int vkey = lane * 2, vdg = wave * 16;
    const __bf16* vsrc = base + (E_DIM + KV_DIM) + g * HD + vdg;
    const __bf16* ksrc = base + E_DIM + g * HD;

    const int klocal = lane >> 3;
    const int kdblk = (lane & 7) ^ (klocal & 7);
    const __bf16* gk_base = ksrc + (size_t)(wave * 32 + klocal) * QKV_N + kdblk * 8;
    __bf16* lk_base = Kls + wave * 2048;

    for (int kv0 = k_lo; kv0 < k_hi; kv0 += 128) {
        // ---- issue async K DMA (block-shared K tile) ----
#pragma unroll
        for (int i = 0; i < 4; ++i)
            async_lds16(gk_base + (size_t)(kv0 + i * 8) * QKV_N, lk_base + i * 512);

        // ---- V global loads (latency overlaps K DMA) ----
        const __bf16* vp = vsrc + (size_t)(kv0 + vkey) * QKV_N;
        uint4 va0 = *(const uint4*)(vp);
        uint4 va1 = *(const uint4*)(vp + 8);
        uint4 vb0 = *(const uint4*)(vp + QKV_N);
        uint4 vb1 = *(const uint4*)(vp + QKV_N + 8);

        {
            const unsigned short* a0 = (const unsigned short*)&va0;
            const unsigned short* a1 = (const unsigned short*)&va1;
            const unsigned short* b0_ = (const unsigned short*)&vb0;
            const unsigned short* b1_ = (const unsigned short*)&vb1;
#pragma unroll
            for (int j = 0; j < 8; ++j) {
                *(uint32_t*)&vT[vdg + j][vkey] = (uint32_t)a0[j] | ((uint32_t)b0_[j] << 16);
                *(uint32_t*)&vT[vdg + 8 + j][vkey] = (uint32_t)a1[j] | ((uint32_t)b1_[j] << 16);
            }
        }
        __syncthreads();          // drains K DMA (vmcnt) + vT visible

        // sub-block 0
        MICRO(kv0, 0, 0);
        if (kv0 < q0)
            MICRO(kv0 + 64, 1, 0);
        // sub-block 1
        MICRO(kv0, 0, 1);
        if (kv0 < q0 + 64)
            MICRO(kv0 + 64, 1, 1);

        __syncthreads();          // all Kls/vT reads done before next tile's staging
    }

    // ---- epilogue ----
    const size_t blk = ((size_t)b * 16 + gp) * 40 + xr;
    const size_t pb = blk * (size_t)(2 * 128 * 64);
#pragma unroll
    for (int qs = 0; qs < 2; ++qs)
#pragma unroll
        for (int h = 0; h < 2; ++h) {
            float lt = l_st[qs][h];
            lt += __shfl_xor(lt, 16);
            lt += __shfl_xor(lt, 32);
            const float inv = 1.f / lt;
            __half* prowO = partO + pb + (size_t)(h * 128 + qs * 64 + qr16) * 64 + quad * 4;
#pragma unroll
            for (int dt = 0; dt < 4; ++dt) {
                __half ob[4];
#pragma unroll
                for (int r = 0; r < 4; ++r) ob[r] = __float2half(o[qs][h][dt][r] * inv);
                *(uint2*)(prowO + dt * 16) = *(const uint2*)ob;
            }
            if (quad == 0)
                partL[blk * 256 + h * 128 + qs * 64 + qr16] = lt;
        }
}

// ---------------- combine partial chunks -> attnb (bf16) ----------------
__global__ __launch_bounds__(256, 4)
void k_combine(const __half* __restrict__ partO, const float* __restrict__ partL,
               __bf16* __restrict__ attnb) {
    const int qh = blockIdx.x, gp = blockIdx.y, b = blockIdx.z;
    const int qi = qh >> 1, h = qh & 1;
    const int nc = (qi >> 2) + 1;
    int x0;
    if (qi < 4) x0 = qi;
    else if (qi < 8) x0 = 4 + (qi - 4) * 2;
    else if (qi < 12) x0 = 12 + (qi - 8) * 3;
    else x0 = 24 + (qi - 12) * 4;

    const int t = threadIdx.x;
    const int row = t >> 1, half = t & 1;   // row = q 0..127
    const int d0 = half * 32;
    const size_t gbase = ((size_t)b * 16 + gp) * 40;

    float W = 0.f;
    float acc[32];
#pragma unroll
    for (int i = 0; i < 32; ++i) acc[i] = 0.f;
    for (int cc = 0; cc < nc; ++cc) {
        const float a = partL[(gbase + x0 + cc) * 256 + h * 128 + row];
        W += a;
        const __half* src = partO + (gbase + x0 + cc) * (size_t)(2 * 128 * 64) +
                            (size_t)(h * 128 + row) * 64 + d0;
#pragma unroll
        for (int i = 0; i < 32; i += 8) {
            uint4 u = *(const uint4*)(src + i);
            const __half* hs = (const __half*)&u;
#pragma unroll
            for (int j = 0; j < 8; ++j) acc[i + j] += a * __half2float(hs[j]);
        }
    }
    const float inv = 1.f / W;
    const int h_abs = (gp >> 1) * 4 + (gp & 1) * 2 + h;
    __bf16* dst = attnb + ((size_t)b * S_LEN + qi * 128 + row) * E_DIM + h_abs * 64 + d0;
#pragma unroll
    for (int i = 0; i < 32; i += 8) {
        __bf16 ob[8];
#pragma unroll
        for (int j = 0; j < 8; ++j) ob[j] = (__bf16)(acc[i + j] * inv);
        *(uint4*)(dst + i) = *(const uint4*)ob;
    }
}

// ---------------- launch ----------------
extern "C" void kernel_launch(void* const* d_in, const int* in_sizes, int n_in,
                              void* d_out, int out_size, void* d_ws, size_t ws_size,
                              hipStream_t stream) {
    const float* x  = (const float*)d_in[0];
    const float* Wq = (const float*)d_in[1];
    const float* Wk = (const float*)d_in[2];
    const float* Wv = (const float*)d_in[3];
    const float* Wo = (const float*)d_in[4];
    const float* bo = (const float*)d_in[5];

    __bf16* xb    = (__bf16*)d_ws;                         // [4096][2048]
    __bf16* WtAll = xb + (size_t)M_ROWS * E_DIM;           // [3072][2048]
    __bf16* WoT   = WtAll + (size_t)QKV_N * E_DIM;         // [2048][2048]
    __bf16* qkv   = WoT + (size_t)E_DIM * E_DIM;           // [4096][3072]
    __bf16* attnb = qkv + (size_t)M_ROWS * QKV_N;          // [4096][2048]
    __half* partO = (__half*)(attnb + (size_t)M_ROWS * E_DIM);    // [1280][2*128*64]
    float* partL  = (float*)(partO + (size_t)1280 * 2 * 128 * 64); // [1280][256]

    k_convert<<<(M_ROWS * E_DIM / 4 + 255) / 256, 256, 0, stream>>>(x, xb, M_ROWS * E_DIM);
    k_transpose_all<<<dim3(64, 64, 4), dim3(32, 8), 0, stream>>>(Wq, Wk, Wv, Wo, WtAll, WoT);

    k_gemm8<<<dim3((M_ROWS / 256) * (QKV_N / 256)), 512, 0, stream>>>(
        xb, WtAll, qkv, M_ROWS, QKV_N, E_DIM);

    k_attn<<<dim3(40, 16, 2), 256, 0, stream>>>(qkv, partO, partL);
    k_combine<<<dim3(32, 16, 2), 256, 0, stream>>>(partO, partL, attnb);

    k_gemm_bt<1><<<dim3(E_DIM / 128, M_ROWS / 128), 256, 0, stream>>>(
        attnb, WoT, d_out, bo, M_ROWS, E_DIM, E_DIM);
}

// Round 10
// 318.286 us; speedup vs baseline: 1.2522x; 1.0287x over previous
//
#include <hip/hip_runtime.h>
#include <hip/hip_fp16.h>

#define E_DIM 2048
#define S_LEN 2048
#define NH 32
#define HD 64
#define KV_DIM 512
#define QKV_N 3072      // E + 2*KV
#define M_ROWS 4096     // B*S
#define QK_SCALE 0.18033688011112042f  // (1/sqrt(64)) * log2(e)

typedef __bf16 bf16x8 __attribute__((ext_vector_type(8)));
typedef float f32x4 __attribute__((ext_vector_type(4)));

__device__ __forceinline__ void async_lds16(const __bf16* g, __bf16* l) {
    __builtin_amdgcn_global_load_lds(
        (const __attribute__((address_space(1))) void*)g,
        (__attribute__((address_space(3))) void*)l, 16, 0, 0);
}

#define BAR() asm volatile("s_barrier" ::: "memory")

// ---------------- fp32 -> bf16 elementwise convert ----------------
__global__ void k_convert(const float* __restrict__ x, __bf16* __restrict__ xb, int n) {
    int i = (blockIdx.x * blockDim.x + threadIdx.x) * 4;
    if (i < n) {
        float4 v = *(const float4*)(x + i);
        xb[i + 0] = (__bf16)v.x;
        xb[i + 1] = (__bf16)v.y;
        xb[i + 2] = (__bf16)v.z;
        xb[i + 3] = (__bf16)v.w;
    }
}

// ---------------- all four weight transposes in one launch ----------------
__global__ void k_transpose_all(const float* __restrict__ Wq, const float* __restrict__ Wk,
                                const float* __restrict__ Wv, const float* __restrict__ Wo,
                                __bf16* __restrict__ WtAll, __bf16* __restrict__ WoT) {
    const int which = blockIdx.z;
    const float* W;
    __bf16* dst;
    int N;
    float scale = 1.f;
    if (which == 0)      { W = Wq; dst = WtAll;                                    N = E_DIM;  scale = QK_SCALE; }
    else if (which == 1) { W = Wk; dst = WtAll + (size_t)E_DIM * E_DIM;            N = KV_DIM; }
    else if (which == 2) { W = Wv; dst = WtAll + (size_t)(E_DIM + KV_DIM) * E_DIM; N = KV_DIM; }
    else                 { W = Wo; dst = WoT;                                      N = E_DIM;  }
    const int n0 = blockIdx.x * 32;
    if (n0 >= N) return;
    const int k0 = blockIdx.y * 32;
    __shared__ float tile[32][33];
    int tx = threadIdx.x, ty = threadIdx.y;
#pragma unroll
    for (int j = 0; j < 4; ++j)
        tile[ty + j * 8][tx] = W[(size_t)(k0 + ty + j * 8) * N + n0 + tx];
    __syncthreads();
#pragma unroll
    for (int j = 0; j < 4; ++j)
        dst[(size_t)(n0 + ty + j * 8) * E_DIM + k0 + tx] = (__bf16)(tile[tx][ty + j * 8] * scale);
}

// ---------------- 256x256 8-phase bf16 GEMM (QKV projection) ----------------
#define STG(g, l, bb, hh, kt) do {                                                              \
    async_lds16((g) + (size_t)((hh) * 128) * K + (size_t)(kt) * 64,                             \
                (l) + (bb) * 16384 + (hh) * 8192);                                              \
    async_lds16((g) + (size_t)((hh) * 128 + 64) * K + (size_t)(kt) * 64,                        \
                (l) + (bb) * 16384 + (hh) * 8192 + 4096);                                       \
} while (0)

#define LDA_(p, mq) do {                                                                        \
    _Pragma("unroll") for (int i_ = 0; i_ < 4; ++i_) {                                          \
        const char* rp_ = pAs + (p) * 32768 + ((mq) * 128 + rA + i_ * 16) * 128;                \
        a[i_][0] = *(const bf16x8*)(rp_ + swzk0);                                               \
        a[i_][1] = *(const bf16x8*)(rp_ + swzk1);                                               \
    }                                                                                           \
} while (0)

#define LDB_(p, nq, b) do {                                                                     \
    _Pragma("unroll") for (int j_ = 0; j_ < 2; ++j_) {                                          \
        const char* rp_ = pBs + (p) * 32768 + ((nq) * 128 + rB + j_ * 16) * 128;                \
        b[j_][0] = *(const bf16x8*)(rp_ + swzk0);                                               \
        b[j_][1] = *(const bf16x8*)(rp_ + swzk1);                                               \
    }                                                                                           \
} while (0)

#define MM(mq, nq, b) do {                                                                      \
    __builtin_amdgcn_s_setprio(1);                                                              \
    _Pragma("unroll") for (int i_ = 0; i_ < 4; ++i_)                                            \
    _Pragma("unroll") for (int j_ = 0; j_ < 2; ++j_) {                                          \
        acc[mq][nq][i_][j_] = __builtin_amdgcn_mfma_f32_16x16x32_bf16(                          \
            a[i_][0], b[j_][0], acc[mq][nq][i_][j_], 0, 0, 0);                                  \
        acc[mq][nq][i_][j_] = __builtin_amdgcn_mfma_f32_16x16x32_bf16(                          \
            a[i_][1], b[j_][1], acc[mq][nq][i_][j_], 0, 0, 0);                                  \
    }                                                                                           \
    __builtin_amdgcn_s_setprio(0);                                                              \
} while (0)

#define GROUP(p, kt, S1, S2, WAITSTMT) do {                                                     \
    LDA_(p, 0);                                                                                 \
    LDB_(p, 0, b0);                                                                             \
    if (S1) STG(gA, lA, (p) ^ 1, 1, (kt) + 1);                                                  \
    BAR(); MM(0, 0, b0); BAR();                                                                 \
    LDB_(p, 1, b1);                                                                             \
    if (S2) STG(gA, lA, (p), 0, (kt) + 2);                                                      \
    BAR(); MM(0, 1, b1); BAR();                                                                 \
    LDA_(p, 1);                                                                                 \
    if (S2) STG(gB, lB, (p), 0, (kt) + 2);                                                      \
    BAR(); MM(1, 1, b1); BAR();                                                                 \
    if (S2) STG(gB, lB, (p), 1, (kt) + 2);                                                      \
    WAITSTMT;                                                                                   \
    BAR(); MM(1, 0, b0); BAR();                                                                 \
} while (0)

__global__ __launch_bounds__(512, 2)
void k_gemm8(const __bf16* __restrict__ A, const __bf16* __restrict__ Bt,
             __bf16* __restrict__ C, int M, int N, int K) {
    __shared__ __attribute__((aligned(16))) __bf16 As[2][16384];
    __shared__ __attribute__((aligned(16))) __bf16 Bs[2][16384];
    const int T = K >> 6;              // K-tiles of 64; requires T >= 3
    const int nbx = N >> 8;
    const int bid = blockIdx.x;
    const int swz = (bid & 7) * ((int)gridDim.x >> 3) + (bid >> 3);
    const int m0 = (swz / nbx) << 8;
    const int n0 = (swz % nbx) << 8;

    const int t = threadIdx.x;
    const int lane = t & 63, w = t >> 6;
    const int quad = lane >> 4, l16 = lane & 15;
    const int wr = w >> 2, wc = w & 3;

    const int rbase = w * 8 + (lane >> 3);
    const int cswz = ((lane & 7) ^ (lane >> 3)) * 8;
    const __bf16* gA = A + (size_t)(m0 + rbase) * K + cswz;
    const __bf16* gB = Bt + (size_t)(n0 + rbase) * K + cswz;
    __bf16* lA = &As[0][0] + w * 512;
    __bf16* lB = &Bs[0][0] + w * 512;

    const int swzk0 = ((0 + quad) ^ (l16 & 7)) * 16;
    const int swzk1 = ((4 + quad) ^ (l16 & 7)) * 16;
    const int rA = wr * 64 + l16;
    const int rB = wc * 32 + l16;
    const char* pAs = (const char*)&As[0][0];
    const char* pBs = (const char*)&Bs[0][0];

    f32x4 acc[2][2][4][2] = {};
    bf16x8 a[4][2], b0[2][2], b1[2][2];

    STG(gA, lA, 0, 0, 0); STG(gA, lA, 0, 1, 0);
    STG(gB, lB, 0, 0, 0); STG(gB, lB, 0, 1, 0);
    STG(gA, lA, 1, 0, 1);
    STG(gB, lB, 1, 0, 1); STG(gB, lB, 1, 1, 1);
    asm volatile("s_waitcnt vmcnt(6)" ::: "memory");
    BAR();

    int p = 0;
    for (int kt = 0; kt < T - 2; ++kt) {
        GROUP(p, kt, 1, 1, asm volatile("s_waitcnt vmcnt(6)" ::: "memory"));
        p ^= 1;
    }
    GROUP(p, T - 2, 1, 0, asm volatile("s_waitcnt vmcnt(0)" ::: "memory"));
    p ^= 1;
    GROUP(p, T - 1, 0, 0, (void)0);

#pragma unroll
    for (int mq = 0; mq < 2; ++mq)
#pragma unroll
        for (int nq = 0; nq < 2; ++nq)
#pragma unroll
            for (int i = 0; i < 4; ++i)
#pragma unroll
                for (int j = 0; j < 2; ++j) {
                    const int row = m0 + mq * 128 + wr * 64 + i * 16 + quad * 4;
                    const int col = n0 + nq * 128 + wc * 32 + j * 16 + l16;
#pragma unroll
                    for (int r = 0; r < 4; ++r)
                        C[(size_t)(row + r) * N + col] = (__bf16)acc[mq][nq][i][j][r];
                }
    (void)M;
}

// ---------------- 128x256 8-phase bf16 GEMM, f32-out + bias (O-projection) ----------------
// BM=128 (one A chunk) x BN=256 (two B chunks); grid 32x8 = 256 blocks (full CU).
// LDS 96 KiB, 1 blk/CU. Chunks/tile = 3: stage B1(t+1)@ph1->p^1, B0(t+2)@ph2->p,
// A(t+2)@after-ph3->p (each after its region's last block-wide reader + barrier).
// Steady vmcnt(4) retires all of tile t+1 (FIFO); tail vmcnt(0); last group pure.
#define STGA_O(bb, kt) do {                                                                     \
    async_lds16(gA + (size_t)(kt) * 64,                  &As[bb][0] + w * 512);                  \
    async_lds16(gA + (size_t)64 * K + (size_t)(kt) * 64, &As[bb][0] + 4096 + w * 512);          \
} while (0)
#define STGB_O(bb, kt, hh) do {                                                                 \
    async_lds16(gB + (size_t)((hh) * 128) * K + (size_t)(kt) * 64,                              \
                &Bs[bb][0] + (hh) * 8192 + w * 512);                                            \
    async_lds16(gB + (size_t)((hh) * 128 + 64) * K + (size_t)(kt) * 64,                         \
                &Bs[bb][0] + (hh) * 8192 + 4096 + w * 512);                                     \
} while (0)

#define LDA_O(p, mq) do {                                                                       \
    _Pragma("unroll") for (int i_ = 0; i_ < 2; ++i_) {                                          \
        const char* rp_ = pAs + (p) * 16384 + ((mq) * 32 + rA + i_ * 16) * 128;                 \
        a[i_][0] = *(const bf16x8*)(rp_ + swzk0);                                               \
        a[i_][1] = *(const bf16x8*)(rp_ + swzk1);                                               \
    }                                                                                           \
} while (0)

#define LDB_O(p, nq, b) do {                                                                    \
    _Pragma("unroll") for (int j_ = 0; j_ < 2; ++j_) {                                          \
        const char* rp_ = pBs + (p) * 32768 + ((nq) * 128 + rB + j_ * 16) * 128;                \
        b[j_][0] = *(const bf16x8*)(rp_ + swzk0);                                               \
        b[j_][1] = *(const bf16x8*)(rp_ + swzk1);                                               \
    }                                                                                           \
} while (0)

#define MM_O(mq, nq, b) do {                                                                    \
    __builtin_amdgcn_s_setprio(1);                                                              \
    _Pragma("unroll") for (int i_ = 0; i_ < 2; ++i_)                                            \
    _Pragma("unroll") for (int j_ = 0; j_ < 2; ++j_) {                                          \
        acc[mq][nq][i_][j_] = __builtin_amdgcn_mfma_f32_16x16x32_bf16(                          \
            a[i_][0], b[j_][0], acc[mq][nq][i_][j_], 0, 0, 0);                                  \
        acc[mq][nq][i_][j_] = __builtin_amdgcn_mfma_f32_16x16x32_bf16(                          \
            a[i_][1], b[j_][1], acc[mq][nq][i_][j_], 0, 0, 0);                                  \
    }                                                                                           \
    __builtin_amdgcn_s_setprio(0);                                                              \
} while (0)

#define GROUP_O(p, kt, S1, S2, WAITSTMT) do {                                                   \
    LDA_O(p, 0);                                                                                \
    LDB_O(p, 0, b0);                                                                            \
    if (S1) STGB_O((p) ^ 1, (kt) + 1, 1);                                                       \
    BAR(); MM_O(0, 0, b0); BAR();                                                               \
    LDB_O(p, 1, b1);                                                                            \
    if (S2) STGB_O(p, (kt) + 2, 0);                                                             \
    BAR(); MM_O(0, 1, b1); BAR();                                                               \
    LDA_O(p, 1);                                                                                \
    BAR(); MM_O(1, 1, b1); BAR();                                                               \
    if (S2) STGA_O(p, (kt) + 2);                                                                \
    WAITSTMT;                                                                                   \
    BAR(); MM_O(1, 0, b0); BAR();                                                               \
} while (0)

__global__ __launch_bounds__(512, 2)
void k_gemm8o(const __bf16* __restrict__ A, const __bf16* __restrict__ Bt,
              float* __restrict__ C, const float* __restrict__ bias,
              int M, int N, int K) {
    __shared__ __attribute__((aligned(16))) __bf16 As[2][8192];    // [buf][128*64]
    __shared__ __attribute__((aligned(16))) __bf16 Bs[2][16384];   // [buf][256*64]
    const int T = K >> 6;
    const int nbx = N >> 8;            // 256-wide N tiles
    const int bid = blockIdx.x;
    const int swz = (bid & 7) * ((int)gridDim.x >> 3) + (bid >> 3);
    const int m0 = (swz / nbx) << 7;   // 128-row M tiles
    const int n0 = (swz % nbx) << 8;

    const int t = threadIdx.x;
    const int lane = t & 63, w = t >> 6;
    const int quad = lane >> 4, l16 = lane & 15;
    const int wr = w >> 2, wc = w & 3;

    const int rbase = w * 8 + (lane >> 3);
    const int cswz = ((lane & 7) ^ (lane >> 3)) * 8;
    const __bf16* gA = A + (size_t)(m0 + rbase) * K + cswz;
    const __bf16* gB = Bt + (size_t)(n0 + rbase) * K + cswz;

    const int swzk0 = ((0 + quad) ^ (l16 & 7)) * 16;
    const int swzk1 = ((4 + quad) ^ (l16 & 7)) * 16;
    const int rA = wr * 64 + l16;      // + mq*32 + i*16 in LDA_O
    const int rB = wc * 32 + l16;
    const char* pAs = (const char*)&As[0][0];
    const char* pBs = (const char*)&Bs[0][0];

    f32x4 acc[2][2][2][2] = {};
    bf16x8 a[2][2], b0[2][2], b1[2][2];

    // prologue: t0 full (A,B0,B1 = 6 asyncs) + t1 (B0,A = 4); drain to 4
    STGA_O(0, 0); STGB_O(0, 0, 0); STGB_O(0, 0, 1);
    STGB_O(1, 1, 0); STGA_O(1, 1);
    asm volatile("s_waitcnt vmcnt(4)" ::: "memory");
    BAR();

    int p = 0;
    for (int kt = 0; kt < T - 2; ++kt) {
        GROUP_O(p, kt, 1, 1, asm volatile("s_waitcnt vmcnt(4)" ::: "memory"));
        p ^= 1;
    }
    GROUP_O(p, T - 2, 1, 0, asm volatile("s_waitcnt vmcnt(0)" ::: "memory"));
    p ^= 1;
    GROUP_O(p, T - 1, 0, 0, (void)0);

#pragma unroll
    for (int mq = 0; mq < 2; ++mq)
#pragma unroll
        for (int nq = 0; nq < 2; ++nq)
#pragma unroll
            for (int i = 0; i < 2; ++i)
#pragma unroll
                for (int j = 0; j < 2; ++j) {
                    const int row = m0 + wr * 64 + mq * 32 + i * 16 + quad * 4;
                    const int col = n0 + nq * 128 + wc * 32 + j * 16 + l16;
#pragma unroll
                    for (int r = 0; r < 4; ++r)
                        C[(size_t)(row + r) * N + col] = acc[mq][nq][i][j][r] + bias[col];
                }
    (void)M;
}

// ---------------- KV-split flash attention (round-2 verified: 91.0 us) ----------------
__global__ __launch_bounds__(256, 3)
void k_attn(const __bf16* __restrict__ qkv, __half* __restrict__ partO,
            float* __restrict__ partL) {
    const int xr = (int)(gridDim.x - 1 - blockIdx.x);   // reversed: biggest blocks first
    int qi, c;
    if (xr < 8)       { qi = xr;                  c = 0; }
    else if (xr < 24) { qi = 8 + ((xr - 8) >> 1); c = (xr - 8) & 1; }
    else if (xr < 48) { qi = 16 + (xr - 24) / 3;  c = (xr - 24) % 3; }
    else              { qi = 24 + ((xr - 48) >> 2); c = (xr - 48) & 3; }
    const int q0 = qi * 64;
    const int k_lo = c * 512;
    const int k_hi = min(k_lo + 512, q0 + 64);

    const int gp = blockIdx.y;
    const int g = gp >> 1;
    const int h0 = g * 4 + (gp & 1) * 2;
    const int b = blockIdx.z;
    const int t = threadIdx.x;
    const int lane = t & 63, wave = t >> 6;
    const int quad = lane >> 4, l16 = lane & 15;

    __shared__ __attribute__((aligned(16))) __bf16 Kls[128 * 64];   // [key][d], swizzled
    __shared__ __attribute__((aligned(16))) __bf16 vT[64][136];     // [d][key 0..127], padded
    __shared__ __attribute__((aligned(16))) __bf16 pT[4][2][1024];  // per-wave P^T

    const __bf16* base = qkv + (size_t)b * S_LEN * QKV_N;
    const int qrow = q0 + wave * 16 + l16;

    bf16x8 qf[2][2];
#pragma unroll
    for (int h = 0; h < 2; ++h)
#pragma unroll
        for (int s = 0; s < 2; ++s)
            qf[h][s] = *(const bf16x8*)(base + (size_t)qrow * QKV_N + (h0 + h) * HD + s * 32 + quad * 8);

    f32x4 o[2][4] = {};
    float l_st[2] = {0.f, 0.f};

    const int vkey = lane * 2, vdg = wave * 16;
    const __bf16* vsrc = base + (E_DIM + KV_DIM) + g * HD + vdg;
    const __bf16* ksrc = base + E_DIM + g * HD;

    const int klocal = lane >> 3;
    const int kdblk = (lane & 7) ^ (klocal & 7);
    const __bf16* gk_base = ksrc + (size_t)(wave * 32 + klocal) * QKV_N + kdblk * 8;
    __bf16* lk_base = Kls + wave * 2048;

    auto qk = [&](int m, f32x4* sA, f32x4* sB) {
        __builtin_amdgcn_s_setprio(1);
#pragma unroll
        for (int kt = 0; kt < 4; ++kt) {
            const int kr = m * 64 + kt * 16 + l16;
            const char* kb_ = (const char*)Kls + kr * 128;
            bf16x8 kf0 = *(const bf16x8*)(kb_ + ((quad ^ (kr & 7)) * 16));
            bf16x8 kf1 = *(const bf16x8*)(kb_ + (((4 + quad) ^ (kr & 7)) * 16));
            f32x4 z = {};
            z = __builtin_amdgcn_mfma_f32_16x16x32_bf16(kf0, qf[0][0], z, 0, 0, 0);
            sA[kt] = __builtin_amdgcn_mfma_f32_16x16x32_bf16(kf1, qf[0][1], z, 0, 0, 0);
            f32x4 ww = {};
            ww = __builtin_amdgcn_mfma_f32_16x16x32_bf16(kf0, qf[1][0], ww, 0, 0, 0);
            sB[kt] = __builtin_amdgcn_mfma_f32_16x16x32_bf16(kf1, qf[1][1], ww, 0, 0, 0);
        }
        __builtin_amdgcn_s_setprio(0);
    };

    auto softmax_p = [&](int kb, int h, f32x4* sc) {
        const bool diag = (kb == q0);
        char* prow = (char*)&pT[wave][h][0] + l16 * 128;
        float lsum = 0.f;
#pragma unroll
        for (int kt = 0; kt < 4; ++kt) {
            f32x4 pv_;
#pragma unroll
            for (int r = 0; r < 4; ++r) pv_[r] = exp2f(sc[kt][r]);
            if (diag) {
                const int kbase = kb + kt * 16 + quad * 4;
#pragma unroll
                for (int r = 0; r < 4; ++r)
                    if (kbase + r > qrow) pv_[r] = 0.f;
            }
#pragma unroll
            for (int r = 0; r < 4; ++r) lsum += pv_[r];
            __bf16 pb[4];
#pragma unroll
            for (int r = 0; r < 4; ++r) pb[r] = (__bf16)pv_[r];
            *(uint2*)(prow + ((2 * kt + (quad >> 1)) ^ (l16 & 7)) * 16 + (quad & 1) * 8) =
                *(const uint2*)pb;
        }
        l_st[h] += lsum;
    };

    auto pv = [&](int m) {
        bf16x8 vf[4][2];
        const int koff = m * 64;
#pragma unroll
        for (int cc = 0; cc < 4; ++cc)
#pragma unroll
            for (int kh = 0; kh < 2; ++kh)
                vf[cc][kh] = *(const bf16x8*)&vT[cc * 16 + l16][koff + kh * 32 + quad * 8];
        __builtin_amdgcn_s_setprio(1);
#pragma unroll
        for (int h = 0; h < 2; ++h) {
            const char* prow = (const char*)&pT[wave][h][0] + l16 * 128;
            bf16x8 pf0 = *(const bf16x8*)(prow + ((0 + quad) ^ (l16 & 7)) * 16);
            bf16x8 pf1 = *(const bf16x8*)(prow + ((4 + quad) ^ (l16 & 7)) * 16);
#pragma unroll
            for (int cc = 0; cc < 4; ++cc) {
                o[h][cc] = __builtin_amdgcn_mfma_f32_16x16x32_bf16(vf[cc][0], pf0, o[h][cc], 0, 0, 0);
                o[h][cc] = __builtin_amdgcn_mfma_f32_16x16x32_bf16(vf[cc][1], pf1, o[h][cc], 0, 0, 0);
            }
        }
        __builtin_amdgcn_s_setprio(0);
    };

    for (int kv0 = k_lo; kv0 < k_hi; kv0 += 128) {
#pragma unroll
        for (int i = 0; i < 4; ++i)
            async_lds16(gk_base + (size_t)(kv0 + i * 8) * QKV_N, lk_base + i * 512);

        const __bf16* vp = vsrc + (size_t)(kv0 + vkey) * QKV_N;
        uint4 va0 = *(const uint4*)(vp);
        uint4 va1 = *(const uint4*)(vp + 8);
        uint4 vb0 = *(const uint4*)(vp + QKV_N);
        uint4 vb1 = *(const uint4*)(vp + QKV_N + 8);

        {
            const unsigned short* a0 = (const unsigned short*)&va0;
            const unsigned short* a1 = (const unsigned short*)&va1;
            const unsigned short* b0_ = (const unsigned short*)&vb0;
            const unsigned short* b1_ = (const unsigned short*)&vb1;
#pragma unroll
            for (int j = 0; j < 8; ++j) {
                *(uint32_t*)&vT[vdg + j][vkey] = (uint32_t)a0[j] | ((uint32_t)b0_[j] << 16);
                *(uint32_t*)&vT[vdg + 8 + j][vkey] = (uint32_t)a1[j] | ((uint32_t)b1_[j] << 16);
            }
        }
        __syncthreads();

        f32x4 scA[4], scB[4];
        qk(0, scA, scB);
        softmax_p(kv0, 0, scA);
        softmax_p(kv0, 1, scB);
        pv(0);

        const int kb1 = kv0 + 64;
        if (kb1 < k_hi) {
            qk(1, scA, scB);
            softmax_p(kb1, 0, scA);
            softmax_p(kb1, 1, scB);
            pv(1);
        }
        __syncthreads();
    }

    const size_t blk = ((size_t)b * 16 + gp) * 80 + xr;
    const size_t pb = blk * (2 * 64 * 64);
#pragma unroll
    for (int h = 0; h < 2; ++h) {
        float lt = l_st[h];
        lt += __shfl_xor(lt, 16);
        lt += __shfl_xor(lt, 32);
        const float inv = 1.f / lt;
        __half* prowO = partO + pb + (size_t)(h * 64 + wave * 16 + l16) * 64 + quad * 4;
#pragma unroll
        for (int dt = 0; dt < 4; ++dt) {
            __half ob[4];
#pragma unroll
            for (int r = 0; r < 4; ++r) ob[r] = __float2half(o[h][dt][r] * inv);
            *(uint2*)(prowO + dt * 16) = *(const uint2*)ob;
        }
        if (quad == 0)
            partL[blk * 128 + h * 64 + wave * 16 + l16] = lt;
    }
}

// ---------------- combine partial chunks -> attnb (bf16) ----------------
__global__ __launch_bounds__(256, 4)
void k_combine(const __half* __restrict__ partO, const float* __restrict__ partL,
               __bf16* __restrict__ attnb) {
    const int qi = blockIdx.x, gp = blockIdx.y, b = blockIdx.z;
    const int nc = (qi >> 3) + 1;
    int x0;
    if (qi < 8) x0 = qi;
    else if (qi < 16) x0 = 8 + (qi - 8) * 2;
    else if (qi < 24) x0 = 24 + (qi - 16) * 3;
    else x0 = 48 + (qi - 24) * 4;

    const int t = threadIdx.x;
    const int row = t >> 1, half = t & 1;
    const int h = row >> 6, q = row & 63;
    const int d0 = half * 32;
    const size_t gbase = ((size_t)b * 16 + gp) * 80;

    float W = 0.f;
    float acc[32];
#pragma unroll
    for (int i = 0; i < 32; ++i) acc[i] = 0.f;
    for (int cc = 0; cc < nc; ++cc) {
        const float a = partL[(gbase + x0 + cc) * 128 + h * 64 + q];
        W += a;
        const __half* src = partO + (gbase + x0 + cc) * (2 * 64 * 64) + (size_t)(h * 64 + q) * 64 + d0;
#pragma unroll
        for (int i = 0; i < 32; i += 8) {
            uint4 u = *(const uint4*)(src + i);
            const __half* hs = (const __half*)&u;
#pragma unroll
            for (int j = 0; j < 8; ++j) acc[i + j] += a * __half2float(hs[j]);
        }
    }
    const float inv = 1.f / W;
    const int h_abs = (gp >> 1) * 4 + (gp & 1) * 2 + h;
    __bf16* dst = attnb + ((size_t)b * S_LEN + qi * 64 + q) * E_DIM + h_abs * 64 + d0;
#pragma unroll
    for (int i = 0; i < 32; i += 8) {
        __bf16 ob[8];
#pragma unroll
        for (int j = 0; j < 8; ++j) ob[j] = (__bf16)(acc[i + j] * inv);
        *(uint4*)(dst + i) = *(const uint4*)ob;
    }
}

// ---------------- launch ----------------
extern "C" void kernel_launch(void* const* d_in, const int* in_sizes, int n_in,
                              void* d_out, int out_size, void* d_ws, size_t ws_size,
                              hipStream_t stream) {
    const float* x  = (const float*)d_in[0];
    const float* Wq = (const float*)d_in[1];
    const float* Wk = (const float*)d_in[2];
    const float* Wv = (const float*)d_in[3];
    const float* Wo = (const float*)d_in[4];
    const float* bo = (const float*)d_in[5];

    __bf16* xb    = (__bf16*)d_ws;                         // [4096][2048]
    __bf16* WtAll = xb + (size_t)M_ROWS * E_DIM;           // [3072][2048]
    __bf16* WoT   = WtAll + (size_t)QKV_N * E_DIM;         // [2048][2048]
    __bf16* qkv   = WoT + (size_t)E_DIM * E_DIM;           // [4096][3072]
    __bf16* attnb = qkv + (size_t)M_ROWS * QKV_N;          // [4096][2048]
    __half* partO = (__half*)(attnb + (size_t)M_ROWS * E_DIM);    // [2560][2*64*64]
    float* partL  = (float*)(partO + (size_t)2560 * 2 * 64 * 64); // [2560][128]

    k_convert<<<(M_ROWS * E_DIM / 4 + 255) / 256, 256, 0, stream>>>(x, xb, M_ROWS * E_DIM);
    k_transpose_all<<<dim3(64, 64, 4), dim3(32, 8), 0, stream>>>(Wq, Wk, Wv, Wo, WtAll, WoT);

    // QKV projection: 256^2 8-phase, grid 192
    k_gemm8<<<dim3((M_ROWS / 256) * (QKV_N / 256)), 512, 0, stream>>>(
        xb, WtAll, qkv, M_ROWS, QKV_N, E_DIM);

    k_attn<<<dim3(80, 16, 2), 256, 0, stream>>>(qkv, partO, partL);
    k_combine<<<dim3(32, 16, 2), 256, 0, stream>>>(partO, partL, attnb);

    // O projection: 128x256 8-phase, grid 32*8 = 256 (full CU coverage)
    k_gemm8o<<<dim3((M_ROWS / 128) * (E_DIM / 256)), 512, 0, stream>>>(
        attnb, WoT, (float*)d_out, bo, M_ROWS, E_DIM, E_DIM);
}